// Round 1
// baseline (1211.434 us; speedup 1.0000x reference)
//
#include <hip/hip_runtime.h>

#define DIMH 1536
#define NH 12
#define DH 128
#define SQ 2048
#define SKV 512
#define FFNH 8960

typedef short short8v __attribute__((ext_vector_type(8)));
typedef short short4v __attribute__((ext_vector_type(4)));
typedef float f32x4 __attribute__((ext_vector_type(4)));

union U8 { unsigned short u[8]; short8v v; };
union U4 { unsigned short u[4]; short4v v; };

__device__ __forceinline__ unsigned short f2bf(float f) {
  unsigned int u = __float_as_uint(f);
  u += 0x7fffu + ((u >> 16) & 1u);
  return (unsigned short)(u >> 16);
}
__device__ __forceinline__ float bf2f(unsigned short u) {
  return __uint_as_float((unsigned int)u << 16);
}

__device__ __forceinline__ void gld16(const void* g, void* l) {
  __builtin_amdgcn_global_load_lds(
      (const __attribute__((address_space(1))) unsigned int*)g,
      (__attribute__((address_space(3))) unsigned int*)l, 16, 0, 0);
}

// ---------------- small elementwise / norm kernels ----------------

__global__ void prep_e(const float* __restrict__ sst, const float* __restrict__ temb,
                       float* __restrict__ e) {
  int i = blockIdx.x * 256 + threadIdx.x;
  if (i < 6 * DIMH) e[i] = sst[i] + temb[i];
}

__global__ void concat4(const float* __restrict__ a, const float* __restrict__ b,
                        const float* __restrict__ c, const float* __restrict__ d,
                        float* __restrict__ o) {
  int i = blockIdx.x * 256 + threadIdx.x;  // 0..6143
  int which = i / DIMH, r = i - which * DIMH;
  float v;
  if (which == 0) v = a[r];
  else if (which == 1) v = b[r];
  else if (which == 2) v = c[r];
  else v = d[r];
  o[i] = v;
}

__global__ void cast_f32_bf16(const float* __restrict__ x, unsigned short* __restrict__ y,
                              int n) {
  int i = blockIdx.x * 256 + threadIdx.x;
  if (i < n) y[i] = f2bf(x[i]);
}

__global__ __launch_bounds__(256) void transpose_bf16(const float* __restrict__ W,
    unsigned short* __restrict__ Wt, int K, int N) {
  __shared__ float T[32][33];
  int n0 = blockIdx.x * 32, k0 = blockIdx.y * 32;
  int tx = threadIdx.x & 31, ty = threadIdx.x >> 5;  // ty 0..7
#pragma unroll
  for (int p = 0; p < 4; p++)
    T[ty + p * 8][tx] = W[(long)(k0 + ty + p * 8) * N + n0 + tx];
  __syncthreads();
#pragma unroll
  for (int p = 0; p < 4; p++)
    Wt[(long)(n0 + ty + p * 8) * K + k0 + tx] = f2bf(T[tx][ty + p * 8]);
}

// bf16 [S, vs] (head-major cols) -> vt[head][d][S]
__global__ __launch_bounds__(256) void vtrans(const unsigned short* __restrict__ v, int vs,
    unsigned short* __restrict__ vt, int S) {
  __shared__ unsigned short T[32][33];
  int s0 = blockIdx.x * 32, c0 = blockIdx.y * 32;
  int tx = threadIdx.x & 31, ty = threadIdx.x >> 5;
#pragma unroll
  for (int p = 0; p < 4; p++)
    T[ty + p * 8][tx] = v[(long)(s0 + ty + p * 8) * vs + c0 + tx];
  __syncthreads();
  int head = c0 / DH, dbase = c0 - head * DH;
#pragma unroll
  for (int p = 0; p < 4; p++)
    vt[(long)head * DH * S + (long)(dbase + ty + p * 8) * S + s0 + tx] = T[tx][ty + p * 8];
}

__device__ __forceinline__ float blockReduceSum(float val) {
  __shared__ float sm[4];
#pragma unroll
  for (int off = 32; off > 0; off >>= 1) val += __shfl_xor(val, off, 64);
  if ((threadIdx.x & 63) == 0) sm[threadIdx.x >> 6] = val;
  __syncthreads();
  val = sm[0] + sm[1] + sm[2] + sm[3];
  __syncthreads();
  return val;
}

// out(bf16) = LN(x_f32) * (g + add1) + b
__global__ __launch_bounds__(256) void layernorm_affine(const float* __restrict__ x,
    unsigned short* __restrict__ out, const float* __restrict__ g,
    const float* __restrict__ b, float add1) {
  long row = blockIdx.x;
  int tid = threadIdx.x;
  const float* xr = x + row * DIMH;
  float v[6];
  float s = 0.f;
#pragma unroll
  for (int i = 0; i < 6; i++) { v[i] = xr[tid + i * 256]; s += v[i]; }
  s = blockReduceSum(s);
  float mean = s * (1.f / DIMH);
  float s2 = 0.f;
#pragma unroll
  for (int i = 0; i < 6; i++) { float d = v[i] - mean; s2 += d * d; }
  s2 = blockReduceSum(s2);
  float inv = rsqrtf(s2 * (1.f / DIMH) + 1e-6f);
  unsigned short* o = out + row * DIMH;
#pragma unroll
  for (int i = 0; i < 6; i++) {
    int c = tid + i * 256;
    o[c] = f2bf((v[i] - mean) * inv * (g[c] + add1) + b[c]);
  }
}

// in-place on bf16 row (row stride xs): x = RMS(x)*w*sc then optional RoPE
__global__ __launch_bounds__(256) void rms_rope(unsigned short* __restrict__ x, int xs,
    const float* __restrict__ w, const float* __restrict__ cosb,
    const float* __restrict__ sinb, int do_rope, float sc) {
  __shared__ float xr[DIMH];
  long row = blockIdx.x;
  int tid = threadIdx.x;
  unsigned short* xp = x + row * xs;
  float ss = 0.f;
#pragma unroll
  for (int i = 0; i < 6; i++) {
    float t = bf2f(xp[tid + i * 256]);
    xr[tid + i * 256] = t;
    ss += t * t;
  }
  ss = blockReduceSum(ss);  // internal syncthreads publishes xr
  float inv = rsqrtf(ss * (1.f / DIMH) + 1e-6f) * sc;
#pragma unroll
  for (int j = 0; j < 3; j++) {
    int p = tid + j * 256;          // pair index 0..767
    int h = p >> 6, i = p & 63;
    int d1 = h * DH + 2 * i;
    float v1 = xr[d1] * inv * w[d1];
    float v2 = xr[d1 + 1] * inv * w[d1 + 1];
    float o1 = v1, o2 = v2;
    if (do_rope) {
      float c = cosb[row * 64 + i], s = sinb[row * 64 + i];
      o1 = v1 * c - v2 * s;
      o2 = v2 * c + v1 * s;
    }
    xp[d1] = f2bf(o1);
    xp[d1 + 1] = f2bf(o2);
  }
}

__global__ void pool64(const unsigned short* __restrict__ src, int ss,
                       float* __restrict__ dst) {
  int c = blockIdx.x * 256 + threadIdx.x;
  int nb = blockIdx.y;
  float s = 0.f;
  for (int j = 0; j < 64; j++) s += bf2f(src[(long)(nb * 64 + j) * ss + c]);
  dst[nb * DIMH + c] = s * (1.f / 64.f);
}

// fine(bf16, stride 1536) += coarse[s/64](f32) * g(bf16, stride gs)
__global__ void combine_fine(unsigned short* __restrict__ fine,
                             const float* __restrict__ coarse,
                             const unsigned short* __restrict__ g, int gs) {
  int i = blockIdx.x * 256 + threadIdx.x;
  int srow = i / DIMH, c = i - srow * DIMH;
  fine[i] = f2bf(bf2f(fine[i]) + coarse[(srow >> 6) * DIMH + c] * bf2f(g[(long)srow * gs + c]));
}

// ---------------- coarse attention (tiny: 12 heads x 32x32, f32) ----------------
// NOTE: qc is pre-scaled by 1/sqrt(D) (folded into rms_rope), so scale=1 here.

__global__ __launch_bounds__(256) void coarse_attn(const float* __restrict__ qc,
    const float* __restrict__ kc, const float* __restrict__ vc, float* __restrict__ co) {
  __shared__ float S[32 * 33];
  int h = blockIdx.x, tid = threadIdx.x;
  for (int e = tid; e < 1024; e += 256) {
    int i = e >> 5, j = e & 31;
    float d = 0.f;
    for (int d0 = 0; d0 < DH; d0++)
      d += qc[i * DIMH + h * DH + d0] * kc[j * DIMH + h * DH + d0];
    S[i * 33 + j] = d;
  }
  __syncthreads();
  if (tid < 32) {
    float m = -3.4e38f;
    for (int j = 0; j < 32; j++) m = fmaxf(m, S[tid * 33 + j]);
    float sum = 0.f;
    for (int j = 0; j < 32; j++) {
      float p = __expf(S[tid * 33 + j] - m);
      S[tid * 33 + j] = p;
      sum += p;
    }
    float r = 1.f / sum;
    for (int j = 0; j < 32; j++) S[tid * 33 + j] *= r;
  }
  __syncthreads();
  for (int e = tid; e < 32 * DH; e += 256) {
    int i = e >> 7, d = e & 127;
    float o = 0.f;
    for (int j = 0; j < 32; j++) o += S[i * 33 + j] * vc[j * DIMH + h * DH + d];
    co[i * DIMH + h * DH + d] = o;
  }
}

// ---------------- flash attention v2: S^T formulation, barrier-free ----------------
// Q pre-scaled by 1/sqrt(D). 128 threads = 2 waves; each wave owns 16 Q rows and
// sweeps its key chunk in 64-t tiles.
// NEW: flash-decoding KV-split via blockIdx.z. When ml != nullptr each block
// processes skchunk keys starting at blockIdx.z*skchunk and writes an
// unnormalized bf16 partial O at O + z*zstride plus (m,l) per (z,h,q) into ml.
// attn_combine merges the partials. This multiplies wave count by the split
// factor (occupancy 17.7% -> ~70%) — the measured bottleneck.

#define LDP 68

__global__ __launch_bounds__(128) void flash2(const unsigned short* __restrict__ Q, int qs,
    const unsigned short* __restrict__ Kx, int kstr, const unsigned short* __restrict__ Vt,
    unsigned short* __restrict__ O, int ostr, int Sk,
    float* __restrict__ ml, long zstride, int skchunk) {
  __shared__ unsigned short P[2][16 * LDP];
  int tid = threadIdx.x;
  int w = tid >> 6, lane = tid & 63;
  int quad = lane >> 4, l16 = lane & 15;
  int h = blockIdx.y;
  int bz = blockIdx.z;
  long q0 = (long)blockIdx.x * 32 + w * 16;
  const unsigned short* Vh = Vt + (long)h * DH * Sk;
  unsigned short* Pw = P[w];

  int t_begin = bz * skchunk;
  int t_end = t_begin + skchunk;
  if (t_end > Sk) t_end = Sk;

  // Q B-frags: Q^T[k=d=quad*8+j][n=q=l16] = Q[q0+l16][d]
  short8v qf[4];
  {
    const unsigned short* qp = Q + (q0 + l16) * qs + h * DH + quad * 8;
#pragma unroll
    for (int kt = 0; kt < 4; kt++) qf[kt] = *(const short8v*)(qp + kt * 32);
  }
  float m_i = -3.4e38f, l_i = 0.f;
  f32x4 o[8];
#pragma unroll
  for (int nt = 0; nt < 8; nt++) o[nt] = (f32x4){0.f, 0.f, 0.f, 0.f};

  for (int t0 = t_begin; t0 < t_end; t0 += 64) {
    // S^T tile: 64 t x 16 q
    f32x4 sc[4];
#pragma unroll
    for (int tt = 0; tt < 4; tt++) {
      f32x4 a = (f32x4){0.f, 0.f, 0.f, 0.f};
      const unsigned short* kp = Kx + (long)(t0 + tt * 16 + l16) * kstr + h * DH + quad * 8;
#pragma unroll
      for (int kt = 0; kt < 4; kt++)
        a = __builtin_amdgcn_mfma_f32_16x16x32_bf16(*(const short8v*)(kp + kt * 32),
                                                    qf[kt], a, 0, 0, 0);
      sc[tt] = a;
    }
    // lane holds 16 t-scores for q=l16 (t = tt*16 + quad*4 + r)
    float mx = -3.4e38f;
#pragma unroll
    for (int tt = 0; tt < 4; tt++)
#pragma unroll
      for (int r = 0; r < 4; r++) mx = fmaxf(mx, sc[tt][r]);
    mx = fmaxf(mx, __shfl_xor(mx, 16, 64));
    mx = fmaxf(mx, __shfl_xor(mx, 32, 64));
    float mnew = fmaxf(m_i, mx);
    float rs = 0.f;
#pragma unroll
    for (int tt = 0; tt < 4; tt++) {
      U4 pk;
#pragma unroll
      for (int r = 0; r < 4; r++) {
        float pe = __expf(sc[tt][r] - mnew);
        rs += pe;
        pk.u[r] = f2bf(pe);
      }
      // t = tt*16 + quad*4 + (0..3), row q=l16: 8B-aligned b64 store
      *(short4v*)&Pw[l16 * LDP + tt * 16 + quad * 4] = pk.v;
    }
    rs += __shfl_xor(rs, 16, 64);
    rs += __shfl_xor(rs, 32, 64);
    float alpha = __expf(m_i - mnew);
    l_i = l_i * alpha + rs;
    m_i = mnew;
    // rescale O (rows q=quad*4+r): fetch alpha for those q's
    float ar[4];
#pragma unroll
    for (int r = 0; r < 4; r++) ar[r] = __shfl(alpha, quad * 4 + r, 16);
#pragma unroll
    for (int nt = 0; nt < 8; nt++) {
      f32x4 t = o[nt];
      t[0] *= ar[0]; t[1] *= ar[1]; t[2] *= ar[2]; t[3] *= ar[3];
      o[nt] = t;
    }
    // PV: A = P[q=l16][t=quad*8+j] (ds_read_b128), B = vt[d][t] (global contiguous)
#pragma unroll
    for (int c = 0; c < 2; c++) {
      short8v ap = *(const short8v*)&Pw[l16 * LDP + c * 32 + quad * 8];
#pragma unroll
      for (int nt = 0; nt < 8; nt++) {
        short8v bv = *(const short8v*)&Vh[(long)(nt * 16 + l16) * Sk + t0 + c * 32 + quad * 8];
        o[nt] = __builtin_amdgcn_mfma_f32_16x16x32_bf16(ap, bv, o[nt], 0, 0, 0);
      }
    }
  }
  if (ml) {
    // partial mode: write unnormalized O (bf16) + per-(z,h,q) running (m,l)
    if (quad == 0) {
      float* mlp = ml + ((size_t)(bz * NH + h) * SQ + q0 + l16) * 2;
      mlp[0] = m_i;
      mlp[1] = l_i;
    }
    unsigned short* Ow = O + (long)bz * zstride;
#pragma unroll
    for (int nt = 0; nt < 8; nt++)
#pragma unroll
      for (int r = 0; r < 4; r++)
        Ow[(q0 + quad * 4 + r) * ostr + h * DH + nt * 16 + l16] = f2bf(o[nt][r]);
  } else {
    float linv[4];
#pragma unroll
    for (int r = 0; r < 4; r++) linv[r] = 1.f / __shfl(l_i, quad * 4 + r, 16);
#pragma unroll
    for (int nt = 0; nt < 8; nt++)
#pragma unroll
      for (int r = 0; r < 4; r++)
        O[(q0 + quad * 4 + r) * ostr + h * DH + nt * 16 + l16] = f2bf(o[nt][r] * linv[r]);
  }
}

// merge nz flash partials: fine[q][c] = sum_z part[z][q][c]*exp(m_z-m*) / l*
// 192 threads x 8 cols each. parts layout: z*(SQ*DIMH) + q*DIMH + c (bf16).
__global__ __launch_bounds__(192) void attn_combine(const unsigned short* __restrict__ parts,
    const float* __restrict__ ml, int nz, unsigned short* __restrict__ fine, int fstr) {
  __shared__ float wgt[4][NH];
  __shared__ float linv[NH];
  int q = blockIdx.x, tid = threadIdx.x;
  if (tid < NH) {
    float m = -3.4e38f;
    for (int z = 0; z < nz; z++)
      m = fmaxf(m, ml[((size_t)(z * NH + tid) * SQ + q) * 2]);
    float l = 0.f;
    for (int z = 0; z < nz; z++) {
      const float* p = &ml[((size_t)(z * NH + tid) * SQ + q) * 2];
      float wz = __expf(p[0] - m);
      wgt[z][tid] = wz;
      l += p[1] * wz;
    }
    linv[tid] = 1.f / l;
  }
  __syncthreads();
  int c0 = tid * 8, h = c0 >> 7;
  float acc[8];
#pragma unroll
  for (int j = 0; j < 8; j++) acc[j] = 0.f;
  for (int z = 0; z < nz; z++) {
    U8 pv;
    pv.v = *(const short8v*)&parts[(size_t)z * SQ * DIMH + (size_t)q * DIMH + c0];
    float wz = wgt[z][h];
#pragma unroll
    for (int j = 0; j < 8; j++) acc[j] += bf2f(pv.u[j]) * wz;
  }
  U8 ov;
  float li = linv[h];
#pragma unroll
  for (int j = 0; j < 8; j++) ov.u[j] = f2bf(acc[j] * li);
  *(short8v*)&fine[(size_t)q * fstr + c0] = ov.v;
}

// ---------------- GEMM v3: A[M,K] bf16 (lda) @ Wt[N,K] bf16 + bias ----------------
// 128x128 tile, BK=64, global_load_lds width-16, XOR-swizzled LDS.
// mode 0: bf16 = v+bias ; 1: bf16 = gelu(v+bias) ; 2: f32 = res + gvec*(v+bias)
// mode 3: bf16 raw partial at out + z*M*ldc (split-K)

__global__ __launch_bounds__(256) void gemm3(const unsigned short* __restrict__ A, int lda,
    const unsigned short* __restrict__ Wt, const float* __restrict__ bias,
    void* __restrict__ outv, int ldc, const float* __restrict__ res,
    const float* __restrict__ gvec, int M, int N, int K, int kchunk, int mode) {
  __shared__ unsigned short As[128 * 64];
  __shared__ unsigned short Bs[128 * 64];
  int tid = threadIdx.x;
  int m0 = blockIdx.x * 128, n0 = blockIdx.y * 128;
  int wave = tid >> 6, lane = tid & 63;
  int quad = lane >> 4, l16 = lane & 15;
  int wm = (wave & 1) * 64, wn = (wave >> 1) * 64;
  int k0 = blockIdx.z * kchunk;
  int k1 = k0 + kchunk; if (k1 > K) k1 = K;

  int rofs = lane >> 3;                      // row within 8-row group
  int schunk = (lane & 7) ^ rofs;            // xor-swizzled 16B chunk read by this lane
  const unsigned short* Ag = A + (long)(m0 + wave * 32 + rofs) * lda + schunk * 8;
  const unsigned short* Bg = Wt + (long)(n0 + wave * 32 + rofs) * (long)K + schunk * 8;
  unsigned short* Albase = &As[(wave * 32) * 64];
  unsigned short* Blbase = &Bs[(wave * 32) * 64];

  f32x4 acc[4][4];
#pragma unroll
  for (int mt = 0; mt < 4; mt++)
#pragma unroll
    for (int nt = 0; nt < 4; nt++) acc[mt][nt] = (f32x4){0.f, 0.f, 0.f, 0.f};

  for (int kb = k0; kb < k1; kb += 64) {
    __syncthreads();
#pragma unroll
    for (int j = 0; j < 4; j++) {
      gld16(Ag + (long)(j * 8) * lda + kb, Albase + (j * 8) * 64);
      gld16(Bg + (long)(j * 8) * K + kb, Blbase + (j * 8) * 64);
    }
    __syncthreads();
#pragma unroll
    for (int ks = 0; ks < 2; ks++) {
      short8v af[4], bfr[4];
#pragma unroll
      for (int mt = 0; mt < 4; mt++) {
        int r = wm + mt * 16 + l16;
        af[mt] = *(const short8v*)&As[r * 64 + (((ks * 4 + quad) ^ (r & 7)) * 8)];
      }
#pragma unroll
      for (int nt = 0; nt < 4; nt++) {
        int r = wn + nt * 16 + l16;
        bfr[nt] = *(const short8v*)&Bs[r * 64 + (((ks * 4 + quad) ^ (r & 7)) * 8)];
      }
#pragma unroll
      for (int mt = 0; mt < 4; mt++)
#pragma unroll
        for (int nt = 0; nt < 4; nt++)
          acc[mt][nt] = __builtin_amdgcn_mfma_f32_16x16x32_bf16(af[mt], bfr[nt], acc[mt][nt], 0, 0, 0);
    }
  }

  long zoff = (mode == 3) ? (long)blockIdx.z * M * (long)ldc : 0;
#pragma unroll
  for (int mt = 0; mt < 4; mt++)
#pragma unroll
    for (int nt = 0; nt < 4; nt++)
#pragma unroll
      for (int r = 0; r < 4; r++) {
        int row = m0 + wm + mt * 16 + quad * 4 + r;
        int col = n0 + wn + nt * 16 + l16;
        float v = acc[mt][nt][r];
        if (bias) v += bias[col];
        if (mode == 1) {
          float z = 0.7978845608028654f * (v + 0.044715f * v * v * v);
          float e2 = __expf(2.f * z);
          float th_ = 1.f - 2.f / (e2 + 1.f);
          v = 0.5f * v * (1.f + th_);
        }
        long idx = (long)row * ldc + col;
        if (mode == 2) {
          float gv = gvec ? gvec[col] : 1.f;
          ((float*)outv)[idx] = res[idx] + gv * v;
        } else {
          ((unsigned short*)outv)[zoff + idx] = f2bf(v);
        }
      }
}

// split-K reduce: out = hid + gvec[col]*(sum_z parts + b2[col])
__global__ void reduce_splitk(const unsigned short* __restrict__ p, int nsplit,
                              const float* __restrict__ hid, const float* __restrict__ b2,
                              const float* __restrict__ gvec, float* __restrict__ out) {
  int i = blockIdx.x * 256 + threadIdx.x;  // SQ*DIMH
  int c = i % DIMH;
  float s = 0.f;
  for (int z = 0; z < nsplit; z++) s += bf2f(p[(long)z * SQ * DIMH + i]);
  out[i] = hid[i] + gvec[c] * (s + b2[c]);
}

// ---------------- launcher ----------------

extern "C" void kernel_launch(void* const* d_in, const int* in_sizes, int n_in,
                              void* d_out, int out_size, void* d_ws, size_t ws_size,
                              hipStream_t stream) {
  (void)in_sizes; (void)n_in; (void)out_size;
  const float* hs   = (const float*)d_in[0];
  const float* enc  = (const float*)d_in[1];
  const float* temb = (const float*)d_in[2];
  const float* rc   = (const float*)d_in[3];
  const float* rsn  = (const float*)d_in[4];
  const float* sst  = (const float*)d_in[5];
  const float* Wq = (const float*)d_in[6];   const float* bq = (const float*)d_in[7];
  const float* Wk = (const float*)d_in[8];   const float* bk = (const float*)d_in[9];
  const float* Wv = (const float*)d_in[10];  const float* bv = (const float*)d_in[11];
  const float* Wg = (const float*)d_in[12];  const float* bg = (const float*)d_in[13];
  const float* Wo = (const float*)d_in[14];  const float* bo = (const float*)d_in[15];
  const float* nq_w = (const float*)d_in[16];  const float* nk_w = (const float*)d_in[17];
  const float* saln_w = (const float*)d_in[18]; const float* saln_b = (const float*)d_in[19];
  const float* cWq = (const float*)d_in[20]; const float* cbq = (const float*)d_in[21];
  const float* cWk = (const float*)d_in[22]; const float* cbk = (const float*)d_in[23];
  const float* cWv = (const float*)d_in[24]; const float* cbv = (const float*)d_in[25];
  const float* cWo = (const float*)d_in[26]; const float* cbo = (const float*)d_in[27];
  const float* cnq_w = (const float*)d_in[28]; const float* cnk_w = (const float*)d_in[29];
  const float* W1 = (const float*)d_in[30];  const float* b1 = (const float*)d_in[31];
  const float* W2 = (const float*)d_in[32];  const float* b2 = (const float*)d_in[33];
  float* outp = (float*)d_out;
  const float attn_scale = 0.08838834764831845f;  // 1/sqrt(128)

  char* base = (char*)d_ws;
  size_t off = 0;
  auto alloc = [&](size_t bytes) -> void* {
    void* p = (void*)(base + off);
    off += (bytes + 255) & ~(size_t)255;
    return p;
  };
  const long ACTE = (long)SQ * DIMH;                 // elements
  float* e     = (float*)alloc(6 * DIMH * 4);
  float* bias4 = (float*)alloc(4 * DIMH * 4);
  unsigned short* nbuf = (unsigned short*)alloc(ACTE * 2);
  unsigned short* R    = (unsigned short*)alloc((size_t)SQ * FFNH * 2);
  float* hid           = (float*)alloc(ACTE * 4);
  unsigned short* WT   = (unsigned short*)alloc((size_t)FFNH * DIMH * 2);
  unsigned short* vt   = (unsigned short*)alloc((size_t)NH * DH * SQ * 2);
  unsigned short* encb = (unsigned short*)alloc((size_t)SKV * DIMH * 2);
  float* qc  = (float*)alloc(32 * DIMH * 4);
  float* kc  = (float*)alloc(32 * DIMH * 4);
  float* vc  = (float*)alloc(32 * DIMH * 4);
  float* cob = (float*)alloc(32 * DIMH * 4);
  float* mlbuf = (float*)alloc((size_t)4 * NH * SQ * 2 * 4);  // flash-split (m,l)
  size_t fixed_off = off;
  int nsplit = 4;
  unsigned short* parts = (unsigned short*)alloc((size_t)4 * ACTE * 2);
  if (off > ws_size) { off = fixed_off; nsplit = 2; parts = (unsigned short*)alloc((size_t)2 * ACTE * 2); }
  if (off > ws_size) { nsplit = 1; }
  // attention KV-split factor: partials live in `parts` (free until FFN2)
  int asplit = (nsplit >= 4) ? 4 : ((nsplit == 2) ? 2 : 1);

  unsigned short* qkvg = R;
  unsigned short* qb   = R;                       // col 0    (stride 6144)
  unsigned short* kb   = R + DIMH;                // col 1536
  unsigned short* vb   = R + 2 * DIMH;            // col 3072
  unsigned short* gb   = R + 3 * DIMH;            // col 4608
  unsigned short* fine = R + 4 * ACTE;            // contiguous stride 1536
  unsigned short* qb2  = R;                       // cross-attn, stride 1536
  unsigned short* kb2  = R + ACTE;
  unsigned short* vb2  = R + ACTE + (long)SKV * DIMH;
  unsigned short* f1   = R;

  prep_e<<<36, 256, 0, stream>>>(sst, temb, e);
  concat4<<<24, 256, 0, stream>>>(bq, bk, bv, bg, bias4);

  layernorm_affine<<<SQ, 256, 0, stream>>>(hs, nbuf, e + DIMH, e, 1.f);

  dim3 tsq(DIMH / 32, DIMH / 32);
  transpose_bf16<<<tsq, 256, 0, stream>>>(Wq, WT + 0L * DIMH * DIMH, DIMH, DIMH);
  transpose_bf16<<<tsq, 256, 0, stream>>>(Wk, WT + 1L * DIMH * DIMH, DIMH, DIMH);
  transpose_bf16<<<tsq, 256, 0, stream>>>(Wv, WT + 2L * DIMH * DIMH, DIMH, DIMH);
  transpose_bf16<<<tsq, 256, 0, stream>>>(Wg, WT + 3L * DIMH * DIMH, DIMH, DIMH);
  gemm3<<<dim3(SQ / 128, 4 * DIMH / 128), 256, 0, stream>>>(
      nbuf, DIMH, WT, bias4, qkvg, 4 * DIMH, nullptr, nullptr, SQ, 4 * DIMH, DIMH, DIMH, 0);

  // q pre-scaled by 1/sqrt(D); k unscaled
  rms_rope<<<SQ, 256, 0, stream>>>(qb, 4 * DIMH, nq_w, rc, rsn, 1, attn_scale);
  rms_rope<<<SQ, 256, 0, stream>>>(kb, 4 * DIMH, nk_w, rc, rsn, 1, 1.f);

  pool64<<<dim3(6, 32), 256, 0, stream>>>(qb, 4 * DIMH, qc);
  pool64<<<dim3(6, 32), 256, 0, stream>>>(kb, 4 * DIMH, kc);
  pool64<<<dim3(6, 32), 256, 0, stream>>>(vb, 4 * DIMH, vc);

  vtrans<<<dim3(SQ / 32, DIMH / 32), 256, 0, stream>>>(vb, 4 * DIMH, vt, SQ);
  if (asplit > 1) {
    flash2<<<dim3(SQ / 32, NH, asplit), 128, 0, stream>>>(qb, 4 * DIMH, kb, 4 * DIMH, vt,
        parts, DIMH, SQ, mlbuf, ACTE, SQ / asplit);
    coarse_attn<<<NH, 256, 0, stream>>>(qc, kc, vc, cob);
    attn_combine<<<SQ, 192, 0, stream>>>(parts, mlbuf, asplit, fine, DIMH);
  } else {
    flash2<<<dim3(SQ / 32, NH), 128, 0, stream>>>(qb, 4 * DIMH, kb, 4 * DIMH, vt,
                                                  fine, DIMH, SQ, nullptr, 0, SQ);
    coarse_attn<<<NH, 256, 0, stream>>>(qc, kc, vc, cob);
  }
  combine_fine<<<SQ * DIMH / 256, 256, 0, stream>>>(fine, cob, gb, 4 * DIMH);

  transpose_bf16<<<tsq, 256, 0, stream>>>(Wo, WT, DIMH, DIMH);
  gemm3<<<dim3(SQ / 128, DIMH / 128), 256, 0, stream>>>(
      fine, DIMH, WT, bo, hid, DIMH, hs, e + 2 * DIMH, SQ, DIMH, DIMH, DIMH, 2);

  layernorm_affine<<<SQ, 256, 0, stream>>>(hid, nbuf, saln_w, saln_b, 0.f);
  transpose_bf16<<<tsq, 256, 0, stream>>>(cWq, WT, DIMH, DIMH);
  gemm3<<<dim3(SQ / 128, DIMH / 128), 256, 0, stream>>>(
      nbuf, DIMH, WT, cbq, qb2, DIMH, nullptr, nullptr, SQ, DIMH, DIMH, DIMH, 0);
  rms_rope<<<SQ, 256, 0, stream>>>(qb2, DIMH, cnq_w, nullptr, nullptr, 0, attn_scale);

  cast_f32_bf16<<<SKV * DIMH / 256, 256, 0, stream>>>(enc, encb, SKV * DIMH);
  transpose_bf16<<<tsq, 256, 0, stream>>>(cWk, WT, DIMH, DIMH);
  gemm3<<<dim3(SKV / 128, DIMH / 128), 256, 0, stream>>>(
      encb, DIMH, WT, cbk, kb2, DIMH, nullptr, nullptr, SKV, DIMH, DIMH, DIMH, 0);
  transpose_bf16<<<tsq, 256, 0, stream>>>(cWv, WT, DIMH, DIMH);
  gemm3<<<dim3(SKV / 128, DIMH / 128), 256, 0, stream>>>(
      encb, DIMH, WT, cbv, vb2, DIMH, nullptr, nullptr, SKV, DIMH, DIMH, DIMH, 0);
  rms_rope<<<SKV, 256, 0, stream>>>(kb2, DIMH, cnk_w, nullptr, nullptr, 0, 1.f);

  vtrans<<<dim3(SKV / 32, DIMH / 32), 256, 0, stream>>>(vb2, DIMH, vt, SKV);
  if (asplit > 1) {
    flash2<<<dim3(SQ / 32, NH, asplit), 128, 0, stream>>>(qb2, DIMH, kb2, DIMH, vt,
        parts, DIMH, SKV, mlbuf, ACTE, SKV / asplit);
    attn_combine<<<SQ, 192, 0, stream>>>(parts, mlbuf, asplit, fine, DIMH);
  } else {
    flash2<<<dim3(SQ / 32, NH), 128, 0, stream>>>(qb2, DIMH, kb2, DIMH, vt,
                                                  fine, DIMH, SKV, nullptr, 0, SKV);
  }
  transpose_bf16<<<tsq, 256, 0, stream>>>(cWo, WT, DIMH, DIMH);
  gemm3<<<dim3(SQ / 128, DIMH / 128), 256, 0, stream>>>(
      fine, DIMH, WT, cbo, hid, DIMH, hid, nullptr, SQ, DIMH, DIMH, DIMH, 2);

  layernorm_affine<<<SQ, 256, 0, stream>>>(hid, nbuf, e + 4 * DIMH, e + 3 * DIMH, 1.f);
  transpose_bf16<<<dim3(FFNH / 32, DIMH / 32), 256, 0, stream>>>(W1, WT, DIMH, FFNH);
  gemm3<<<dim3(SQ / 128, FFNH / 128), 256, 0, stream>>>(
      nbuf, DIMH, WT, b1, f1, FFNH, nullptr, nullptr, SQ, FFNH, DIMH, DIMH, 1);
  transpose_bf16<<<dim3(DIMH / 32, FFNH / 32), 256, 0, stream>>>(W2, WT, FFNH, DIMH);
  if (nsplit == 1) {
    gemm3<<<dim3(SQ / 128, DIMH / 128), 256, 0, stream>>>(
        f1, FFNH, WT, b2, outp, DIMH, hid, e + 5 * DIMH, SQ, DIMH, FFNH, FFNH, 2);
  } else {
    gemm3<<<dim3(SQ / 128, DIMH / 128, nsplit), 256, 0, stream>>>(
        f1, FFNH, WT, nullptr, parts, DIMH, nullptr, nullptr, SQ, DIMH, FFNH, FFNH / nsplit, 3);
    reduce_splitk<<<SQ * DIMH / 256, 256, 0, stream>>>(parts, nsplit, hid, b2,
                                                       e + 5 * DIMH, outp);
  }
}

// Round 2
// 1018.253 us; speedup vs baseline: 1.1897x; 1.1897x over previous
//
#include <hip/hip_runtime.h>

#define DIMH 1536
#define NH 12
#define DH 128
#define SQ 2048
#define SKV 512
#define FFNH 8960

typedef short short8v __attribute__((ext_vector_type(8)));
typedef short short4v __attribute__((ext_vector_type(4)));
typedef float f32x4 __attribute__((ext_vector_type(4)));

union U8 { unsigned short u[8]; short8v v; };
union U4 { unsigned short u[4]; short4v v; };

__device__ __forceinline__ unsigned short f2bf(float f) {
  unsigned int u = __float_as_uint(f);
  u += 0x7fffu + ((u >> 16) & 1u);
  return (unsigned short)(u >> 16);
}
__device__ __forceinline__ float bf2f(unsigned short u) {
  return __uint_as_float((unsigned int)u << 16);
}

__device__ __forceinline__ void gld16(const void* g, void* l) {
  __builtin_amdgcn_global_load_lds(
      (const __attribute__((address_space(1))) unsigned int*)g,
      (__attribute__((address_space(3))) unsigned int*)l, 16, 0, 0);
}

// ---------------- small elementwise / norm kernels ----------------

__global__ void prep_e(const float* __restrict__ sst, const float* __restrict__ temb,
                       float* __restrict__ e) {
  int i = blockIdx.x * 256 + threadIdx.x;
  if (i < 6 * DIMH) e[i] = sst[i] + temb[i];
}

__global__ void concat4(const float* __restrict__ a, const float* __restrict__ b,
                        const float* __restrict__ c, const float* __restrict__ d,
                        float* __restrict__ o) {
  int i = blockIdx.x * 256 + threadIdx.x;  // 0..6143
  int which = i / DIMH, r = i - which * DIMH;
  float v;
  if (which == 0) v = a[r];
  else if (which == 1) v = b[r];
  else if (which == 2) v = c[r];
  else v = d[r];
  o[i] = v;
}

__global__ void cast_f32_bf16(const float* __restrict__ x, unsigned short* __restrict__ y,
                              int n) {
  int i = blockIdx.x * 256 + threadIdx.x;
  if (i < n) y[i] = f2bf(x[i]);
}

__global__ __launch_bounds__(256) void transpose_bf16(const float* __restrict__ W,
    unsigned short* __restrict__ Wt, int K, int N) {
  __shared__ float T[32][33];
  int n0 = blockIdx.x * 32, k0 = blockIdx.y * 32;
  int tx = threadIdx.x & 31, ty = threadIdx.x >> 5;  // ty 0..7
#pragma unroll
  for (int p = 0; p < 4; p++)
    T[ty + p * 8][tx] = W[(long)(k0 + ty + p * 8) * N + n0 + tx];
  __syncthreads();
#pragma unroll
  for (int p = 0; p < 4; p++)
    Wt[(long)(n0 + ty + p * 8) * K + k0 + tx] = f2bf(T[tx][ty + p * 8]);
}

// bf16 [S, vs] (head-major cols) -> vt[head][d][S]
__global__ __launch_bounds__(256) void vtrans(const unsigned short* __restrict__ v, int vs,
    unsigned short* __restrict__ vt, int S) {
  __shared__ unsigned short T[32][33];
  int s0 = blockIdx.x * 32, c0 = blockIdx.y * 32;
  int tx = threadIdx.x & 31, ty = threadIdx.x >> 5;
#pragma unroll
  for (int p = 0; p < 4; p++)
    T[ty + p * 8][tx] = v[(long)(s0 + ty + p * 8) * vs + c0 + tx];
  __syncthreads();
  int head = c0 / DH, dbase = c0 - head * DH;
#pragma unroll
  for (int p = 0; p < 4; p++)
    vt[(long)head * DH * S + (long)(dbase + ty + p * 8) * S + s0 + tx] = T[tx][ty + p * 8];
}

__device__ __forceinline__ float blockReduceSum(float val) {
  __shared__ float sm[4];
#pragma unroll
  for (int off = 32; off > 0; off >>= 1) val += __shfl_xor(val, off, 64);
  if ((threadIdx.x & 63) == 0) sm[threadIdx.x >> 6] = val;
  __syncthreads();
  val = sm[0] + sm[1] + sm[2] + sm[3];
  __syncthreads();
  return val;
}

// out(bf16) = LN(x_f32) * (g + add1) + b
__global__ __launch_bounds__(256) void layernorm_affine(const float* __restrict__ x,
    unsigned short* __restrict__ out, const float* __restrict__ g,
    const float* __restrict__ b, float add1) {
  long row = blockIdx.x;
  int tid = threadIdx.x;
  const float* xr = x + row * DIMH;
  float v[6];
  float s = 0.f;
#pragma unroll
  for (int i = 0; i < 6; i++) { v[i] = xr[tid + i * 256]; s += v[i]; }
  s = blockReduceSum(s);
  float mean = s * (1.f / DIMH);
  float s2 = 0.f;
#pragma unroll
  for (int i = 0; i < 6; i++) { float d = v[i] - mean; s2 += d * d; }
  s2 = blockReduceSum(s2);
  float inv = rsqrtf(s2 * (1.f / DIMH) + 1e-6f);
  unsigned short* o = out + row * DIMH;
#pragma unroll
  for (int i = 0; i < 6; i++) {
    int c = tid + i * 256;
    o[c] = f2bf((v[i] - mean) * inv * (g[c] + add1) + b[c]);
  }
}

// in-place on bf16 row (row stride xs): x = RMS(x)*w*sc then optional RoPE
__global__ __launch_bounds__(256) void rms_rope(unsigned short* __restrict__ x, int xs,
    const float* __restrict__ w, const float* __restrict__ cosb,
    const float* __restrict__ sinb, int do_rope, float sc) {
  __shared__ float xr[DIMH];
  long row = blockIdx.x;
  int tid = threadIdx.x;
  unsigned short* xp = x + row * xs;
  float ss = 0.f;
#pragma unroll
  for (int i = 0; i < 6; i++) {
    float t = bf2f(xp[tid + i * 256]);
    xr[tid + i * 256] = t;
    ss += t * t;
  }
  ss = blockReduceSum(ss);  // internal syncthreads publishes xr
  float inv = rsqrtf(ss * (1.f / DIMH) + 1e-6f) * sc;
#pragma unroll
  for (int j = 0; j < 3; j++) {
    int p = tid + j * 256;          // pair index 0..767
    int h = p >> 6, i = p & 63;
    int d1 = h * DH + 2 * i;
    float v1 = xr[d1] * inv * w[d1];
    float v2 = xr[d1 + 1] * inv * w[d1 + 1];
    float o1 = v1, o2 = v2;
    if (do_rope) {
      float c = cosb[row * 64 + i], s = sinb[row * 64 + i];
      o1 = v1 * c - v2 * s;
      o2 = v2 * c + v1 * s;
    }
    xp[d1] = f2bf(o1);
    xp[d1 + 1] = f2bf(o2);
  }
}

__global__ void pool64(const unsigned short* __restrict__ src, int ss,
                       float* __restrict__ dst) {
  int c = blockIdx.x * 256 + threadIdx.x;
  int nb = blockIdx.y;
  float s = 0.f;
  for (int j = 0; j < 64; j++) s += bf2f(src[(long)(nb * 64 + j) * ss + c]);
  dst[nb * DIMH + c] = s * (1.f / 64.f);
}

// fine(bf16, stride 1536) += coarse[s/64](f32) * g(bf16, stride gs)
__global__ void combine_fine(unsigned short* __restrict__ fine,
                             const float* __restrict__ coarse,
                             const unsigned short* __restrict__ g, int gs) {
  int i = blockIdx.x * 256 + threadIdx.x;
  int srow = i / DIMH, c = i - srow * DIMH;
  fine[i] = f2bf(bf2f(fine[i]) + coarse[(srow >> 6) * DIMH + c] * bf2f(g[(long)srow * gs + c]));
}

// ---------------- coarse attention (tiny: 12 heads x 32x32, f32) ----------------
// NOTE: qc is pre-scaled by 1/sqrt(D) (folded into rms_rope), so scale=1 here.

__global__ __launch_bounds__(256) void coarse_attn(const float* __restrict__ qc,
    const float* __restrict__ kc, const float* __restrict__ vc, float* __restrict__ co) {
  __shared__ float S[32 * 33];
  int h = blockIdx.x, tid = threadIdx.x;
  for (int e = tid; e < 1024; e += 256) {
    int i = e >> 5, j = e & 31;
    float d = 0.f;
    for (int d0 = 0; d0 < DH; d0++)
      d += qc[i * DIMH + h * DH + d0] * kc[j * DIMH + h * DH + d0];
    S[i * 33 + j] = d;
  }
  __syncthreads();
  if (tid < 32) {
    float m = -3.4e38f;
    for (int j = 0; j < 32; j++) m = fmaxf(m, S[tid * 33 + j]);
    float sum = 0.f;
    for (int j = 0; j < 32; j++) {
      float p = __expf(S[tid * 33 + j] - m);
      S[tid * 33 + j] = p;
      sum += p;
    }
    float r = 1.f / sum;
    for (int j = 0; j < 32; j++) S[tid * 33 + j] *= r;
  }
  __syncthreads();
  for (int e = tid; e < 32 * DH; e += 256) {
    int i = e >> 7, d = e & 127;
    float o = 0.f;
    for (int j = 0; j < 32; j++) o += S[i * 33 + j] * vc[j * DIMH + h * DH + d];
    co[i * DIMH + h * DH + d] = o;
  }
}

// ---------------- flash attention v3: LDS-shared K/V tiles ----------------
// Round-1 post-mortem: 4x parallelism left flash2's time unchanged -> it was
// saturating the vector-memory request path (each wave issued 32 scattered
// 16-lanes-x-16B gathers per 64-key tile, duplicated across waves/blocks).
// v3: 256 threads / 4 waves, Q-tile 64. Per tile the BLOCK stages K(64x128)
// and V^T(128x64) into LDS with global_load_lds (coalesced, 32 instrs/block =
// 4x fewer VMEM instructions + 4x fewer cache-line transactions), XOR-swizzled
// via pre-swizzled global source (LDS dest must stay linear). Fragment
// ds_read_b128 reads are conflict-free under the swizzle (uniform bank-quad
// distribution). Per-wave softmax/P/epilogue unchanged from flash2.
// KV-split z (flash-decoding) kept at 2: 768 blocks = 3 blocks/CU = exactly
// the LDS residency limit (41.5 KB/block).

#define LDP 68

__global__ __launch_bounds__(256, 3) void flash3(const unsigned short* __restrict__ Q, int qs,
    const unsigned short* __restrict__ Kx, int kstr, const unsigned short* __restrict__ Vt,
    unsigned short* __restrict__ O, int ostr, int Sk,
    float* __restrict__ ml, long zstride, int skchunk) {
  __shared__ unsigned short Ks[64 * 128];   // [t][d], 16B-chunk XOR-swizzled by (t&7)
  __shared__ unsigned short Vs[128 * 64];   // [d][t], 16B-chunk XOR-swizzled by (d&7)
  __shared__ unsigned short P[4][16 * LDP];
  int tid = threadIdx.x;
  int w = tid >> 6, lane = tid & 63;
  int quad = lane >> 4, l16 = lane & 15;
  int h = blockIdx.y, bz = blockIdx.z;
  long q0 = (long)blockIdx.x * 64 + w * 16;
  const unsigned short* Vh = Vt + (long)h * DH * Sk;
  unsigned short* Pw = P[w];

  int t_begin = bz * skchunk;
  int t_end = t_begin + skchunk;
  if (t_end > Sk) t_end = Sk;

  // K staging: instr j stages rows [w*16+j*4, +4). LDS (r,c) <- global chunk c^(r&7).
  // r&7 = (j&1)*4 + rK, and (j&1)*4 + rK == ((j&1)*4) ^ rK since rK<4.
  int rK = lane >> 4, cK = lane & 15;
  const unsigned short* KgA = Kx + (long)(w * 16 + rK) * kstr + h * DH + (cK ^ rK) * 8;
  const unsigned short* KgB = Kx + (long)(w * 16 + rK) * kstr + h * DH + ((cK ^ rK) ^ 4) * 8;
  // V staging: instr j stages d-rows [w*32+j*8, +8); d&7 = rV for all j.
  int rV = lane >> 3, cV = lane & 7;
  const unsigned short* Vg = Vh + (long)(w * 32 + rV) * Sk + (cV ^ rV) * 8;

  // Q B-frags: Q^T[k=d=quad*8+j][n=q=l16] = Q[q0+l16][d]
  short8v qf[4];
  {
    const unsigned short* qp = Q + (q0 + l16) * qs + h * DH + quad * 8;
#pragma unroll
    for (int kt = 0; kt < 4; kt++) qf[kt] = *(const short8v*)(qp + kt * 32);
  }
  float m_i = -3.4e38f, l_i = 0.f;
  f32x4 o[8];
#pragma unroll
  for (int nt = 0; nt < 8; nt++) o[nt] = (f32x4){0.f, 0.f, 0.f, 0.f};

  int kch[4];
#pragma unroll
  for (int kt = 0; kt < 4; kt++) kch[kt] = ((kt * 4 + quad) ^ (l16 & 7)) * 8;

  for (int t0 = t_begin; t0 < t_end; t0 += 64) {
    __syncthreads();  // previous tile's LDS reads complete
#pragma unroll
    for (int j = 0; j < 4; j++) {
      const unsigned short* ksrc = (j & 1) ? KgB : KgA;
      gld16(ksrc + (long)(t0 + j * 4) * kstr, &Ks[(w * 16 + j * 4) * 128]);
      gld16(Vg + (long)(j * 8) * Sk + t0, &Vs[(w * 32 + j * 8) * 64]);
    }
    __syncthreads();  // staged data visible (compiler inserts vmcnt(0))

    // S^T tile: 64 t x 16 q. A-frag = K[t=tt*16+l16][d-chunk kt*4+quad] from LDS.
    f32x4 sc[4];
#pragma unroll
    for (int tt = 0; tt < 4; tt++) {
      const unsigned short* kr = &Ks[(tt * 16 + l16) * 128];
      f32x4 a = (f32x4){0.f, 0.f, 0.f, 0.f};
#pragma unroll
      for (int kt = 0; kt < 4; kt++)
        a = __builtin_amdgcn_mfma_f32_16x16x32_bf16(*(const short8v*)(kr + kch[kt]),
                                                    qf[kt], a, 0, 0, 0);
      sc[tt] = a;
    }
    // lane holds 16 t-scores for q=l16 (t = tt*16 + quad*4 + r)
    float mx = -3.4e38f;
#pragma unroll
    for (int tt = 0; tt < 4; tt++)
#pragma unroll
      for (int r = 0; r < 4; r++) mx = fmaxf(mx, sc[tt][r]);
    mx = fmaxf(mx, __shfl_xor(mx, 16, 64));
    mx = fmaxf(mx, __shfl_xor(mx, 32, 64));
    float mnew = fmaxf(m_i, mx);
    float rs = 0.f;
#pragma unroll
    for (int tt = 0; tt < 4; tt++) {
      U4 pk;
#pragma unroll
      for (int r = 0; r < 4; r++) {
        float pe = __expf(sc[tt][r] - mnew);
        rs += pe;
        pk.u[r] = f2bf(pe);
      }
      *(short4v*)&Pw[l16 * LDP + tt * 16 + quad * 4] = pk.v;
    }
    rs += __shfl_xor(rs, 16, 64);
    rs += __shfl_xor(rs, 32, 64);
    float alpha = __expf(m_i - mnew);
    l_i = l_i * alpha + rs;
    m_i = mnew;
    float ar[4];
#pragma unroll
    for (int r = 0; r < 4; r++) ar[r] = __shfl(alpha, quad * 4 + r, 16);
#pragma unroll
    for (int nt = 0; nt < 8; nt++) {
      f32x4 t = o[nt];
      t[0] *= ar[0]; t[1] *= ar[1]; t[2] *= ar[2]; t[3] *= ar[3];
      o[nt] = t;
    }
    // PV: A = P[q=l16][t=quad*8+j] (LDS), B = Vs[d=nt*16+l16][t-chunk c*4+quad] (LDS)
#pragma unroll
    for (int c = 0; c < 2; c++) {
      short8v ap = *(const short8v*)&Pw[l16 * LDP + c * 32 + quad * 8];
#pragma unroll
      for (int nt = 0; nt < 8; nt++) {
        short8v bv = *(const short8v*)&Vs[(nt * 16 + l16) * 64 +
                                          (((c * 4 + quad) ^ (l16 & 7)) * 8)];
        o[nt] = __builtin_amdgcn_mfma_f32_16x16x32_bf16(ap, bv, o[nt], 0, 0, 0);
      }
    }
  }
  if (ml) {
    // partial mode: write unnormalized O (bf16) + per-(z,h,q) running (m,l)
    if (quad == 0) {
      float* mlp = ml + ((size_t)(bz * NH + h) * SQ + q0 + l16) * 2;
      mlp[0] = m_i;
      mlp[1] = l_i;
    }
    unsigned short* Ow = O + (long)bz * zstride;
#pragma unroll
    for (int nt = 0; nt < 8; nt++)
#pragma unroll
      for (int r = 0; r < 4; r++)
        Ow[(q0 + quad * 4 + r) * ostr + h * DH + nt * 16 + l16] = f2bf(o[nt][r]);
  } else {
    float linv[4];
#pragma unroll
    for (int r = 0; r < 4; r++) linv[r] = 1.f / __shfl(l_i, quad * 4 + r, 16);
#pragma unroll
    for (int nt = 0; nt < 8; nt++)
#pragma unroll
      for (int r = 0; r < 4; r++)
        O[(q0 + quad * 4 + r) * ostr + h * DH + nt * 16 + l16] = f2bf(o[nt][r] * linv[r]);
  }
}

// merge nz flash partials: fine[q][c] = sum_z part[z][q][c]*exp(m_z-m*) / l*
// 192 threads x 8 cols each. parts layout: z*(SQ*DIMH) + q*DIMH + c (bf16).
__global__ __launch_bounds__(192) void attn_combine(const unsigned short* __restrict__ parts,
    const float* __restrict__ ml, int nz, unsigned short* __restrict__ fine, int fstr) {
  __shared__ float wgt[4][NH];
  __shared__ float linv[NH];
  int q = blockIdx.x, tid = threadIdx.x;
  if (tid < NH) {
    float m = -3.4e38f;
    for (int z = 0; z < nz; z++)
      m = fmaxf(m, ml[((size_t)(z * NH + tid) * SQ + q) * 2]);
    float l = 0.f;
    for (int z = 0; z < nz; z++) {
      const float* p = &ml[((size_t)(z * NH + tid) * SQ + q) * 2];
      float wz = __expf(p[0] - m);
      wgt[z][tid] = wz;
      l += p[1] * wz;
    }
    linv[tid] = 1.f / l;
  }
  __syncthreads();
  int c0 = tid * 8, h = c0 >> 7;
  float acc[8];
#pragma unroll
  for (int j = 0; j < 8; j++) acc[j] = 0.f;
  for (int z = 0; z < nz; z++) {
    U8 pv;
    pv.v = *(const short8v*)&parts[(size_t)z * SQ * DIMH + (size_t)q * DIMH + c0];
    float wz = wgt[z][h];
#pragma unroll
    for (int j = 0; j < 8; j++) acc[j] += bf2f(pv.u[j]) * wz;
  }
  U8 ov;
  float li = linv[h];
#pragma unroll
  for (int j = 0; j < 8; j++) ov.u[j] = f2bf(acc[j] * li);
  *(short8v*)&fine[(size_t)q * fstr + c0] = ov.v;
}

// ---------------- GEMM v3: A[M,K] bf16 (lda) @ Wt[N,K] bf16 + bias ----------------
// 128x128 tile, BK=64, global_load_lds width-16, XOR-swizzled LDS.
// mode 0: bf16 = v+bias ; 1: bf16 = gelu(v+bias) ; 2: f32 = res + gvec*(v+bias)
// mode 3: bf16 raw partial at out + z*M*ldc (split-K)

__global__ __launch_bounds__(256) void gemm3(const unsigned short* __restrict__ A, int lda,
    const unsigned short* __restrict__ Wt, const float* __restrict__ bias,
    void* __restrict__ outv, int ldc, const float* __restrict__ res,
    const float* __restrict__ gvec, int M, int N, int K, int kchunk, int mode) {
  __shared__ unsigned short As[128 * 64];
  __shared__ unsigned short Bs[128 * 64];
  int tid = threadIdx.x;
  int m0 = blockIdx.x * 128, n0 = blockIdx.y * 128;
  int wave = tid >> 6, lane = tid & 63;
  int quad = lane >> 4, l16 = lane & 15;
  int wm = (wave & 1) * 64, wn = (wave >> 1) * 64;
  int k0 = blockIdx.z * kchunk;
  int k1 = k0 + kchunk; if (k1 > K) k1 = K;

  int rofs = lane >> 3;                      // row within 8-row group
  int schunk = (lane & 7) ^ rofs;            // xor-swizzled 16B chunk read by this lane
  const unsigned short* Ag = A + (long)(m0 + wave * 32 + rofs) * lda + schunk * 8;
  const unsigned short* Bg = Wt + (long)(n0 + wave * 32 + rofs) * (long)K + schunk * 8;
  unsigned short* Albase = &As[(wave * 32) * 64];
  unsigned short* Blbase = &Bs[(wave * 32) * 64];

  f32x4 acc[4][4];
#pragma unroll
  for (int mt = 0; mt < 4; mt++)
#pragma unroll
    for (int nt = 0; nt < 4; nt++) acc[mt][nt] = (f32x4){0.f, 0.f, 0.f, 0.f};

  for (int kb = k0; kb < k1; kb += 64) {
    __syncthreads();
#pragma unroll
    for (int j = 0; j < 4; j++) {
      gld16(Ag + (long)(j * 8) * lda + kb, Albase + (j * 8) * 64);
      gld16(Bg + (long)(j * 8) * K + kb, Blbase + (j * 8) * 64);
    }
    __syncthreads();
#pragma unroll
    for (int ks = 0; ks < 2; ks++) {
      short8v af[4], bfr[4];
#pragma unroll
      for (int mt = 0; mt < 4; mt++) {
        int r = wm + mt * 16 + l16;
        af[mt] = *(const short8v*)&As[r * 64 + (((ks * 4 + quad) ^ (r & 7)) * 8)];
      }
#pragma unroll
      for (int nt = 0; nt < 4; nt++) {
        int r = wn + nt * 16 + l16;
        bfr[nt] = *(const short8v*)&Bs[r * 64 + (((ks * 4 + quad) ^ (r & 7)) * 8)];
      }
#pragma unroll
      for (int mt = 0; mt < 4; mt++)
#pragma unroll
        for (int nt = 0; nt < 4; nt++)
          acc[mt][nt] = __builtin_amdgcn_mfma_f32_16x16x32_bf16(af[mt], bfr[nt], acc[mt][nt], 0, 0, 0);
    }
  }

  long zoff = (mode == 3) ? (long)blockIdx.z * M * (long)ldc : 0;
#pragma unroll
  for (int mt = 0; mt < 4; mt++)
#pragma unroll
    for (int nt = 0; nt < 4; nt++)
#pragma unroll
      for (int r = 0; r < 4; r++) {
        int row = m0 + wm + mt * 16 + quad * 4 + r;
        int col = n0 + wn + nt * 16 + l16;
        float v = acc[mt][nt][r];
        if (bias) v += bias[col];
        if (mode == 1) {
          float z = 0.7978845608028654f * (v + 0.044715f * v * v * v);
          float e2 = __expf(2.f * z);
          float th_ = 1.f - 2.f / (e2 + 1.f);
          v = 0.5f * v * (1.f + th_);
        }
        long idx = (long)row * ldc + col;
        if (mode == 2) {
          float gv = gvec ? gvec[col] : 1.f;
          ((float*)outv)[idx] = res[idx] + gv * v;
        } else {
          ((unsigned short*)outv)[zoff + idx] = f2bf(v);
        }
      }
}

// split-K reduce: out = hid + gvec[col]*(sum_z parts + b2[col])
__global__ void reduce_splitk(const unsigned short* __restrict__ p, int nsplit,
                              const float* __restrict__ hid, const float* __restrict__ b2,
                              const float* __restrict__ gvec, float* __restrict__ out) {
  int i = blockIdx.x * 256 + threadIdx.x;  // SQ*DIMH
  int c = i % DIMH;
  float s = 0.f;
  for (int z = 0; z < nsplit; z++) s += bf2f(p[(long)z * SQ * DIMH + i]);
  out[i] = hid[i] + gvec[c] * (s + b2[c]);
}

// ---------------- launcher ----------------

extern "C" void kernel_launch(void* const* d_in, const int* in_sizes, int n_in,
                              void* d_out, int out_size, void* d_ws, size_t ws_size,
                              hipStream_t stream) {
  (void)in_sizes; (void)n_in; (void)out_size;
  const float* hs   = (const float*)d_in[0];
  const float* enc  = (const float*)d_in[1];
  const float* temb = (const float*)d_in[2];
  const float* rc   = (const float*)d_in[3];
  const float* rsn  = (const float*)d_in[4];
  const float* sst  = (const float*)d_in[5];
  const float* Wq = (const float*)d_in[6];   const float* bq = (const float*)d_in[7];
  const float* Wk = (const float*)d_in[8];   const float* bk = (const float*)d_in[9];
  const float* Wv = (const float*)d_in[10];  const float* bv = (const float*)d_in[11];
  const float* Wg = (const float*)d_in[12];  const float* bg = (const float*)d_in[13];
  const float* Wo = (const float*)d_in[14];  const float* bo = (const float*)d_in[15];
  const float* nq_w = (const float*)d_in[16];  const float* nk_w = (const float*)d_in[17];
  const float* saln_w = (const float*)d_in[18]; const float* saln_b = (const float*)d_in[19];
  const float* cWq = (const float*)d_in[20]; const float* cbq = (const float*)d_in[21];
  const float* cWk = (const float*)d_in[22]; const float* cbk = (const float*)d_in[23];
  const float* cWv = (const float*)d_in[24]; const float* cbv = (const float*)d_in[25];
  const float* cWo = (const float*)d_in[26]; const float* cbo = (const float*)d_in[27];
  const float* cnq_w = (const float*)d_in[28]; const float* cnk_w = (const float*)d_in[29];
  const float* W1 = (const float*)d_in[30];  const float* b1 = (const float*)d_in[31];
  const float* W2 = (const float*)d_in[32];  const float* b2 = (const float*)d_in[33];
  float* outp = (float*)d_out;
  const float attn_scale = 0.08838834764831845f;  // 1/sqrt(128)

  char* base = (char*)d_ws;
  size_t off = 0;
  auto alloc = [&](size_t bytes) -> void* {
    void* p = (void*)(base + off);
    off += (bytes + 255) & ~(size_t)255;
    return p;
  };
  const long ACTE = (long)SQ * DIMH;                 // elements
  float* e     = (float*)alloc(6 * DIMH * 4);
  float* bias4 = (float*)alloc(4 * DIMH * 4);
  unsigned short* nbuf = (unsigned short*)alloc(ACTE * 2);
  unsigned short* R    = (unsigned short*)alloc((size_t)SQ * FFNH * 2);
  float* hid           = (float*)alloc(ACTE * 4);
  unsigned short* WT   = (unsigned short*)alloc((size_t)FFNH * DIMH * 2);
  unsigned short* vt   = (unsigned short*)alloc((size_t)NH * DH * SQ * 2);
  unsigned short* encb = (unsigned short*)alloc((size_t)SKV * DIMH * 2);
  float* qc  = (float*)alloc(32 * DIMH * 4);
  float* kc  = (float*)alloc(32 * DIMH * 4);
  float* vc  = (float*)alloc(32 * DIMH * 4);
  float* cob = (float*)alloc(32 * DIMH * 4);
  float* mlbuf = (float*)alloc((size_t)4 * NH * SQ * 2 * 4);  // flash-split (m,l)
  size_t fixed_off = off;
  int nsplit = 4;
  unsigned short* parts = (unsigned short*)alloc((size_t)4 * ACTE * 2);
  if (off > ws_size) { off = fixed_off; nsplit = 2; parts = (unsigned short*)alloc((size_t)2 * ACTE * 2); }
  if (off > ws_size) { nsplit = 1; }
  // attention KV-split factor: 2 -> 768 blocks = 3 blocks/CU (the LDS limit)
  int asplit = (nsplit >= 2) ? 2 : 1;

  unsigned short* qkvg = R;
  unsigned short* qb   = R;                       // col 0    (stride 6144)
  unsigned short* kb   = R + DIMH;                // col 1536
  unsigned short* vb   = R + 2 * DIMH;            // col 3072
  unsigned short* gb   = R + 3 * DIMH;            // col 4608
  unsigned short* fine = R + 4 * ACTE;            // contiguous stride 1536
  unsigned short* qb2  = R;                       // cross-attn, stride 1536
  unsigned short* kb2  = R + ACTE;
  unsigned short* vb2  = R + ACTE + (long)SKV * DIMH;
  unsigned short* f1   = R;

  prep_e<<<36, 256, 0, stream>>>(sst, temb, e);
  concat4<<<24, 256, 0, stream>>>(bq, bk, bv, bg, bias4);

  layernorm_affine<<<SQ, 256, 0, stream>>>(hs, nbuf, e + DIMH, e, 1.f);

  dim3 tsq(DIMH / 32, DIMH / 32);
  transpose_bf16<<<tsq, 256, 0, stream>>>(Wq, WT + 0L * DIMH * DIMH, DIMH, DIMH);
  transpose_bf16<<<tsq, 256, 0, stream>>>(Wk, WT + 1L * DIMH * DIMH, DIMH, DIMH);
  transpose_bf16<<<tsq, 256, 0, stream>>>(Wv, WT + 2L * DIMH * DIMH, DIMH, DIMH);
  transpose_bf16<<<tsq, 256, 0, stream>>>(Wg, WT + 3L * DIMH * DIMH, DIMH, DIMH);
  gemm3<<<dim3(SQ / 128, 4 * DIMH / 128), 256, 0, stream>>>(
      nbuf, DIMH, WT, bias4, qkvg, 4 * DIMH, nullptr, nullptr, SQ, 4 * DIMH, DIMH, DIMH, 0);

  // q pre-scaled by 1/sqrt(D); k unscaled
  rms_rope<<<SQ, 256, 0, stream>>>(qb, 4 * DIMH, nq_w, rc, rsn, 1, attn_scale);
  rms_rope<<<SQ, 256, 0, stream>>>(kb, 4 * DIMH, nk_w, rc, rsn, 1, 1.f);

  pool64<<<dim3(6, 32), 256, 0, stream>>>(qb, 4 * DIMH, qc);
  pool64<<<dim3(6, 32), 256, 0, stream>>>(kb, 4 * DIMH, kc);
  pool64<<<dim3(6, 32), 256, 0, stream>>>(vb, 4 * DIMH, vc);

  vtrans<<<dim3(SQ / 32, DIMH / 32), 256, 0, stream>>>(vb, 4 * DIMH, vt, SQ);
  if (asplit > 1) {
    flash3<<<dim3(SQ / 64, NH, asplit), 256, 0, stream>>>(qb, 4 * DIMH, kb, 4 * DIMH, vt,
        parts, DIMH, SQ, mlbuf, ACTE, SQ / asplit);
    coarse_attn<<<NH, 256, 0, stream>>>(qc, kc, vc, cob);
    attn_combine<<<SQ, 192, 0, stream>>>(parts, mlbuf, asplit, fine, DIMH);
  } else {
    flash3<<<dim3(SQ / 64, NH), 256, 0, stream>>>(qb, 4 * DIMH, kb, 4 * DIMH, vt,
                                                  fine, DIMH, SQ, nullptr, 0, SQ);
    coarse_attn<<<NH, 256, 0, stream>>>(qc, kc, vc, cob);
  }
  combine_fine<<<SQ * DIMH / 256, 256, 0, stream>>>(fine, cob, gb, 4 * DIMH);

  transpose_bf16<<<tsq, 256, 0, stream>>>(Wo, WT, DIMH, DIMH);
  gemm3<<<dim3(SQ / 128, DIMH / 128), 256, 0, stream>>>(
      fine, DIMH, WT, bo, hid, DIMH, hs, e + 2 * DIMH, SQ, DIMH, DIMH, DIMH, 2);

  layernorm_affine<<<SQ, 256, 0, stream>>>(hid, nbuf, saln_w, saln_b, 0.f);
  transpose_bf16<<<tsq, 256, 0, stream>>>(cWq, WT, DIMH, DIMH);
  gemm3<<<dim3(SQ / 128, DIMH / 128), 256, 0, stream>>>(
      nbuf, DIMH, WT, cbq, qb2, DIMH, nullptr, nullptr, SQ, DIMH, DIMH, DIMH, 0);
  rms_rope<<<SQ, 256, 0, stream>>>(qb2, DIMH, cnq_w, nullptr, nullptr, 0, attn_scale);

  cast_f32_bf16<<<SKV * DIMH / 256, 256, 0, stream>>>(enc, encb, SKV * DIMH);
  transpose_bf16<<<tsq, 256, 0, stream>>>(cWk, WT, DIMH, DIMH);
  gemm3<<<dim3(SKV / 128, DIMH / 128), 256, 0, stream>>>(
      encb, DIMH, WT, cbk, kb2, DIMH, nullptr, nullptr, SKV, DIMH, DIMH, DIMH, 0);
  transpose_bf16<<<tsq, 256, 0, stream>>>(cWv, WT, DIMH, DIMH);
  gemm3<<<dim3(SKV / 128, DIMH / 128), 256, 0, stream>>>(
      encb, DIMH, WT, cbv, vb2, DIMH, nullptr, nullptr, SKV, DIMH, DIMH, DIMH, 0);
  rms_rope<<<SKV, 256, 0, stream>>>(kb2, DIMH, cnk_w, nullptr, nullptr, 0, 1.f);

  vtrans<<<dim3(SKV / 32, DIMH / 32), 256, 0, stream>>>(vb2, DIMH, vt, SKV);
  if (asplit > 1) {
    flash3<<<dim3(SQ / 64, NH, asplit), 256, 0, stream>>>(qb2, DIMH, kb2, DIMH, vt,
        parts, DIMH, SKV, mlbuf, ACTE, SKV / asplit);
    attn_combine<<<SQ, 192, 0, stream>>>(parts, mlbuf, asplit, fine, DIMH);
  } else {
    flash3<<<dim3(SQ / 64, NH), 256, 0, stream>>>(qb2, DIMH, kb2, DIMH, vt,
                                                  fine, DIMH, SKV, nullptr, 0, SKV);
  }
  transpose_bf16<<<tsq, 256, 0, stream>>>(cWo, WT, DIMH, DIMH);
  gemm3<<<dim3(SQ / 128, DIMH / 128), 256, 0, stream>>>(
      fine, DIMH, WT, cbo, hid, DIMH, hid, nullptr, SQ, DIMH, DIMH, DIMH, 2);

  layernorm_affine<<<SQ, 256, 0, stream>>>(hid, nbuf, e + 4 * DIMH, e + 3 * DIMH, 1.f);
  transpose_bf16<<<dim3(FFNH / 32, DIMH / 32), 256, 0, stream>>>(W1, WT, DIMH, FFNH);
  gemm3<<<dim3(SQ / 128, FFNH / 128), 256, 0, stream>>>(
      nbuf, DIMH, WT, b1, f1, FFNH, nullptr, nullptr, SQ, FFNH, DIMH, DIMH, 1);
  transpose_bf16<<<dim3(DIMH / 32, FFNH / 32), 256, 0, stream>>>(W2, WT, FFNH, DIMH);
  if (nsplit == 1) {
    gemm3<<<dim3(SQ / 128, DIMH / 128), 256, 0, stream>>>(
        f1, FFNH, WT, b2, outp, DIMH, hid, e + 5 * DIMH, SQ, DIMH, FFNH, FFNH, 2);
  } else {
    gemm3<<<dim3(SQ / 128, DIMH / 128, nsplit), 256, 0, stream>>>(
        f1, FFNH, WT, nullptr, parts, DIMH, nullptr, nullptr, SQ, DIMH, FFNH, FFNH / nsplit, 3);
    reduce_splitk<<<SQ * DIMH / 256, 256, 0, stream>>>(parts, nsplit, hid, b2,
                                                       e + 5 * DIMH, outp);
  }
}

// Round 3
// 958.252 us; speedup vs baseline: 1.2642x; 1.0626x over previous
//
#include <hip/hip_runtime.h>

#define DIMH 1536
#define NH 12
#define DH 128
#define SQ 2048
#define SKV 512
#define FFNH 8960

typedef short short8v __attribute__((ext_vector_type(8)));
typedef short short4v __attribute__((ext_vector_type(4)));
typedef float f32x4 __attribute__((ext_vector_type(4)));

union U8 { unsigned short u[8]; short8v v; };
union U4 { unsigned short u[4]; short4v v; };

__device__ __forceinline__ unsigned short f2bf(float f) {
  unsigned int u = __float_as_uint(f);
  u += 0x7fffu + ((u >> 16) & 1u);
  return (unsigned short)(u >> 16);
}
__device__ __forceinline__ float bf2f(unsigned short u) {
  return __uint_as_float((unsigned int)u << 16);
}

__device__ __forceinline__ void gld16(const void* g, void* l) {
  __builtin_amdgcn_global_load_lds(
      (const __attribute__((address_space(1))) unsigned int*)g,
      (__attribute__((address_space(3))) unsigned int*)l, 16, 0, 0);
}

// ---------------- small elementwise / norm kernels ----------------

__global__ void prep_e(const float* __restrict__ sst, const float* __restrict__ temb,
                       float* __restrict__ e) {
  int i = blockIdx.x * 256 + threadIdx.x;
  if (i < 6 * DIMH) e[i] = sst[i] + temb[i];
}

__global__ void concat4(const float* __restrict__ a, const float* __restrict__ b,
                        const float* __restrict__ c, const float* __restrict__ d,
                        float* __restrict__ o) {
  int i = blockIdx.x * 256 + threadIdx.x;  // 0..6143
  int which = i / DIMH, r = i - which * DIMH;
  float v;
  if (which == 0) v = a[r];
  else if (which == 1) v = b[r];
  else if (which == 2) v = c[r];
  else v = d[r];
  o[i] = v;
}

__global__ void cast_f32_bf16(const float* __restrict__ x, unsigned short* __restrict__ y,
                              int n) {
  int i = blockIdx.x * 256 + threadIdx.x;
  if (i < n) y[i] = f2bf(x[i]);
}

__global__ __launch_bounds__(256) void transpose_bf16(const float* __restrict__ W,
    unsigned short* __restrict__ Wt, int K, int N) {
  __shared__ float T[32][33];
  int n0 = blockIdx.x * 32, k0 = blockIdx.y * 32;
  int tx = threadIdx.x & 31, ty = threadIdx.x >> 5;  // ty 0..7
#pragma unroll
  for (int p = 0; p < 4; p++)
    T[ty + p * 8][tx] = W[(long)(k0 + ty + p * 8) * N + n0 + tx];
  __syncthreads();
#pragma unroll
  for (int p = 0; p < 4; p++)
    Wt[(long)(n0 + ty + p * 8) * K + k0 + tx] = f2bf(T[tx][ty + p * 8]);
}

// bf16 [S, vs] (head-major cols) -> vt[head][d][S]
__global__ __launch_bounds__(256) void vtrans(const unsigned short* __restrict__ v, int vs,
    unsigned short* __restrict__ vt, int S) {
  __shared__ unsigned short T[32][33];
  int s0 = blockIdx.x * 32, c0 = blockIdx.y * 32;
  int tx = threadIdx.x & 31, ty = threadIdx.x >> 5;
#pragma unroll
  for (int p = 0; p < 4; p++)
    T[ty + p * 8][tx] = v[(long)(s0 + ty + p * 8) * vs + c0 + tx];
  __syncthreads();
  int head = c0 / DH, dbase = c0 - head * DH;
#pragma unroll
  for (int p = 0; p < 4; p++)
    vt[(long)head * DH * S + (long)(dbase + ty + p * 8) * S + s0 + tx] = T[tx][ty + p * 8];
}

__device__ __forceinline__ float blockReduceSum(float val) {
  __shared__ float sm[4];
#pragma unroll
  for (int off = 32; off > 0; off >>= 1) val += __shfl_xor(val, off, 64);
  if ((threadIdx.x & 63) == 0) sm[threadIdx.x >> 6] = val;
  __syncthreads();
  val = sm[0] + sm[1] + sm[2] + sm[3];
  __syncthreads();
  return val;
}

// out(bf16) = LN(x_f32) * (g + add1) + b
__global__ __launch_bounds__(256) void layernorm_affine(const float* __restrict__ x,
    unsigned short* __restrict__ out, const float* __restrict__ g,
    const float* __restrict__ b, float add1) {
  long row = blockIdx.x;
  int tid = threadIdx.x;
  const float* xr = x + row * DIMH;
  float v[6];
  float s = 0.f;
#pragma unroll
  for (int i = 0; i < 6; i++) { v[i] = xr[tid + i * 256]; s += v[i]; }
  s = blockReduceSum(s);
  float mean = s * (1.f / DIMH);
  float s2 = 0.f;
#pragma unroll
  for (int i = 0; i < 6; i++) { float d = v[i] - mean; s2 += d * d; }
  s2 = blockReduceSum(s2);
  float inv = rsqrtf(s2 * (1.f / DIMH) + 1e-6f);
  unsigned short* o = out + row * DIMH;
#pragma unroll
  for (int i = 0; i < 6; i++) {
    int c = tid + i * 256;
    o[c] = f2bf((v[i] - mean) * inv * (g[c] + add1) + b[c]);
  }
}

// in-place on bf16 row (row stride xs): x = RMS(x)*w*sc then optional RoPE
__global__ __launch_bounds__(256) void rms_rope(unsigned short* __restrict__ x, int xs,
    const float* __restrict__ w, const float* __restrict__ cosb,
    const float* __restrict__ sinb, int do_rope, float sc) {
  __shared__ float xr[DIMH];
  long row = blockIdx.x;
  int tid = threadIdx.x;
  unsigned short* xp = x + row * xs;
  float ss = 0.f;
#pragma unroll
  for (int i = 0; i < 6; i++) {
    float t = bf2f(xp[tid + i * 256]);
    xr[tid + i * 256] = t;
    ss += t * t;
  }
  ss = blockReduceSum(ss);  // internal syncthreads publishes xr
  float inv = rsqrtf(ss * (1.f / DIMH) + 1e-6f) * sc;
#pragma unroll
  for (int j = 0; j < 3; j++) {
    int p = tid + j * 256;          // pair index 0..767
    int h = p >> 6, i = p & 63;
    int d1 = h * DH + 2 * i;
    float v1 = xr[d1] * inv * w[d1];
    float v2 = xr[d1 + 1] * inv * w[d1 + 1];
    float o1 = v1, o2 = v2;
    if (do_rope) {
      float c = cosb[row * 64 + i], s = sinb[row * 64 + i];
      o1 = v1 * c - v2 * s;
      o2 = v2 * c + v1 * s;
    }
    xp[d1] = f2bf(o1);
    xp[d1 + 1] = f2bf(o2);
  }
}

__global__ void pool64(const unsigned short* __restrict__ src, int ss,
                       float* __restrict__ dst) {
  int c = blockIdx.x * 256 + threadIdx.x;
  int nb = blockIdx.y;
  float s = 0.f;
  for (int j = 0; j < 64; j++) s += bf2f(src[(long)(nb * 64 + j) * ss + c]);
  dst[nb * DIMH + c] = s * (1.f / 64.f);
}

// fine(bf16, stride 1536) += coarse[s/64](f32) * g(bf16, stride gs)
__global__ void combine_fine(unsigned short* __restrict__ fine,
                             const float* __restrict__ coarse,
                             const unsigned short* __restrict__ g, int gs) {
  int i = blockIdx.x * 256 + threadIdx.x;
  int srow = i / DIMH, c = i - srow * DIMH;
  fine[i] = f2bf(bf2f(fine[i]) + coarse[(srow >> 6) * DIMH + c] * bf2f(g[(long)srow * gs + c]));
}

// ---------------- coarse attention (tiny: 12 heads x 32x32, f32) ----------------
// NOTE: qc is pre-scaled by 1/sqrt(D) (folded into rms_rope), so scale=1 here.

__global__ __launch_bounds__(256) void coarse_attn(const float* __restrict__ qc,
    const float* __restrict__ kc, const float* __restrict__ vc, float* __restrict__ co) {
  __shared__ float S[32 * 33];
  int h = blockIdx.x, tid = threadIdx.x;
  for (int e = tid; e < 1024; e += 256) {
    int i = e >> 5, j = e & 31;
    float d = 0.f;
    for (int d0 = 0; d0 < DH; d0++)
      d += qc[i * DIMH + h * DH + d0] * kc[j * DIMH + h * DH + d0];
    S[i * 33 + j] = d;
  }
  __syncthreads();
  if (tid < 32) {
    float m = -3.4e38f;
    for (int j = 0; j < 32; j++) m = fmaxf(m, S[tid * 33 + j]);
    float sum = 0.f;
    for (int j = 0; j < 32; j++) {
      float p = __expf(S[tid * 33 + j] - m);
      S[tid * 33 + j] = p;
      sum += p;
    }
    float r = 1.f / sum;
    for (int j = 0; j < 32; j++) S[tid * 33 + j] *= r;
  }
  __syncthreads();
  for (int e = tid; e < 32 * DH; e += 256) {
    int i = e >> 7, d = e & 127;
    float o = 0.f;
    for (int j = 0; j < 32; j++) o += S[i * 33 + j] * vc[j * DIMH + h * DH + d];
    co[i * DIMH + h * DH + d] = o;
  }
}

// ---------------- flash attention v3: LDS-shared K/V tiles ----------------
// (verified in round 2: self-attn 204 -> off the top-5; keep as-is)

#define LDP 68

__global__ __launch_bounds__(256, 3) void flash3(const unsigned short* __restrict__ Q, int qs,
    const unsigned short* __restrict__ Kx, int kstr, const unsigned short* __restrict__ Vt,
    unsigned short* __restrict__ O, int ostr, int Sk,
    float* __restrict__ ml, long zstride, int skchunk) {
  __shared__ unsigned short Ks[64 * 128];   // [t][d], 16B-chunk XOR-swizzled by (t&7)
  __shared__ unsigned short Vs[128 * 64];   // [d][t], 16B-chunk XOR-swizzled by (d&7)
  __shared__ unsigned short P[4][16 * LDP];
  int tid = threadIdx.x;
  int w = tid >> 6, lane = tid & 63;
  int quad = lane >> 4, l16 = lane & 15;
  int h = blockIdx.y, bz = blockIdx.z;
  long q0 = (long)blockIdx.x * 64 + w * 16;
  const unsigned short* Vh = Vt + (long)h * DH * Sk;
  unsigned short* Pw = P[w];

  int t_begin = bz * skchunk;
  int t_end = t_begin + skchunk;
  if (t_end > Sk) t_end = Sk;

  // K staging: instr j stages rows [w*16+j*4, +4). LDS (r,c) <- global chunk c^(r&7).
  int rK = lane >> 4, cK = lane & 15;
  const unsigned short* KgA = Kx + (long)(w * 16 + rK) * kstr + h * DH + (cK ^ rK) * 8;
  const unsigned short* KgB = Kx + (long)(w * 16 + rK) * kstr + h * DH + ((cK ^ rK) ^ 4) * 8;
  // V staging: instr j stages d-rows [w*32+j*8, +8); d&7 = rV for all j.
  int rV = lane >> 3, cV = lane & 7;
  const unsigned short* Vg = Vh + (long)(w * 32 + rV) * Sk + (cV ^ rV) * 8;

  // Q B-frags: Q^T[k=d=quad*8+j][n=q=l16] = Q[q0+l16][d]
  short8v qf[4];
  {
    const unsigned short* qp = Q + (q0 + l16) * qs + h * DH + quad * 8;
#pragma unroll
    for (int kt = 0; kt < 4; kt++) qf[kt] = *(const short8v*)(qp + kt * 32);
  }
  float m_i = -3.4e38f, l_i = 0.f;
  f32x4 o[8];
#pragma unroll
  for (int nt = 0; nt < 8; nt++) o[nt] = (f32x4){0.f, 0.f, 0.f, 0.f};

  int kch[4];
#pragma unroll
  for (int kt = 0; kt < 4; kt++) kch[kt] = ((kt * 4 + quad) ^ (l16 & 7)) * 8;

  for (int t0 = t_begin; t0 < t_end; t0 += 64) {
    __syncthreads();  // previous tile's LDS reads complete
#pragma unroll
    for (int j = 0; j < 4; j++) {
      const unsigned short* ksrc = (j & 1) ? KgB : KgA;
      gld16(ksrc + (long)(t0 + j * 4) * kstr, &Ks[(w * 16 + j * 4) * 128]);
      gld16(Vg + (long)(j * 8) * Sk + t0, &Vs[(w * 32 + j * 8) * 64]);
    }
    __syncthreads();  // staged data visible

    // S^T tile: 64 t x 16 q. A-frag = K[t=tt*16+l16][d-chunk kt*4+quad] from LDS.
    f32x4 sc[4];
#pragma unroll
    for (int tt = 0; tt < 4; tt++) {
      const unsigned short* kr = &Ks[(tt * 16 + l16) * 128];
      f32x4 a = (f32x4){0.f, 0.f, 0.f, 0.f};
#pragma unroll
      for (int kt = 0; kt < 4; kt++)
        a = __builtin_amdgcn_mfma_f32_16x16x32_bf16(*(const short8v*)(kr + kch[kt]),
                                                    qf[kt], a, 0, 0, 0);
      sc[tt] = a;
    }
    // lane holds 16 t-scores for q=l16 (t = tt*16 + quad*4 + r)
    float mx = -3.4e38f;
#pragma unroll
    for (int tt = 0; tt < 4; tt++)
#pragma unroll
      for (int r = 0; r < 4; r++) mx = fmaxf(mx, sc[tt][r]);
    mx = fmaxf(mx, __shfl_xor(mx, 16, 64));
    mx = fmaxf(mx, __shfl_xor(mx, 32, 64));
    float mnew = fmaxf(m_i, mx);
    float rs = 0.f;
#pragma unroll
    for (int tt = 0; tt < 4; tt++) {
      U4 pk;
#pragma unroll
      for (int r = 0; r < 4; r++) {
        float pe = __expf(sc[tt][r] - mnew);
        rs += pe;
        pk.u[r] = f2bf(pe);
      }
      *(short4v*)&Pw[l16 * LDP + tt * 16 + quad * 4] = pk.v;
    }
    rs += __shfl_xor(rs, 16, 64);
    rs += __shfl_xor(rs, 32, 64);
    float alpha = __expf(m_i - mnew);
    l_i = l_i * alpha + rs;
    m_i = mnew;
    float ar[4];
#pragma unroll
    for (int r = 0; r < 4; r++) ar[r] = __shfl(alpha, quad * 4 + r, 16);
#pragma unroll
    for (int nt = 0; nt < 8; nt++) {
      f32x4 t = o[nt];
      t[0] *= ar[0]; t[1] *= ar[1]; t[2] *= ar[2]; t[3] *= ar[3];
      o[nt] = t;
    }
    // PV: A = P[q=l16][t=quad*8+j] (LDS), B = Vs[d=nt*16+l16][t-chunk c*4+quad] (LDS)
#pragma unroll
    for (int c = 0; c < 2; c++) {
      short8v ap = *(const short8v*)&Pw[l16 * LDP + c * 32 + quad * 8];
#pragma unroll
      for (int nt = 0; nt < 8; nt++) {
        short8v bv = *(const short8v*)&Vs[(nt * 16 + l16) * 64 +
                                          (((c * 4 + quad) ^ (l16 & 7)) * 8)];
        o[nt] = __builtin_amdgcn_mfma_f32_16x16x32_bf16(ap, bv, o[nt], 0, 0, 0);
      }
    }
  }
  if (ml) {
    // partial mode: write unnormalized O (bf16) + per-(z,h,q) running (m,l)
    if (quad == 0) {
      float* mlp = ml + ((size_t)(bz * NH + h) * SQ + q0 + l16) * 2;
      mlp[0] = m_i;
      mlp[1] = l_i;
    }
    unsigned short* Ow = O + (long)bz * zstride;
#pragma unroll
    for (int nt = 0; nt < 8; nt++)
#pragma unroll
      for (int r = 0; r < 4; r++)
        Ow[(q0 + quad * 4 + r) * ostr + h * DH + nt * 16 + l16] = f2bf(o[nt][r]);
  } else {
    float linv[4];
#pragma unroll
    for (int r = 0; r < 4; r++) linv[r] = 1.f / __shfl(l_i, quad * 4 + r, 16);
#pragma unroll
    for (int nt = 0; nt < 8; nt++)
#pragma unroll
      for (int r = 0; r < 4; r++)
        O[(q0 + quad * 4 + r) * ostr + h * DH + nt * 16 + l16] = f2bf(o[nt][r] * linv[r]);
  }
}

// merge nz flash partials: fine[q][c] = sum_z part[z][q][c]*exp(m_z-m*) / l*
__global__ __launch_bounds__(192) void attn_combine(const unsigned short* __restrict__ parts,
    const float* __restrict__ ml, int nz, unsigned short* __restrict__ fine, int fstr) {
  __shared__ float wgt[4][NH];
  __shared__ float linv[NH];
  int q = blockIdx.x, tid = threadIdx.x;
  if (tid < NH) {
    float m = -3.4e38f;
    for (int z = 0; z < nz; z++)
      m = fmaxf(m, ml[((size_t)(z * NH + tid) * SQ + q) * 2]);
    float l = 0.f;
    for (int z = 0; z < nz; z++) {
      const float* p = &ml[((size_t)(z * NH + tid) * SQ + q) * 2];
      float wz = __expf(p[0] - m);
      wgt[z][tid] = wz;
      l += p[1] * wz;
    }
    linv[tid] = 1.f / l;
  }
  __syncthreads();
  int c0 = tid * 8, h = c0 >> 7;
  float acc[8];
#pragma unroll
  for (int j = 0; j < 8; j++) acc[j] = 0.f;
  for (int z = 0; z < nz; z++) {
    U8 pv;
    pv.v = *(const short8v*)&parts[(size_t)z * SQ * DIMH + (size_t)q * DIMH + c0];
    float wz = wgt[z][h];
#pragma unroll
    for (int j = 0; j < 8; j++) acc[j] += bf2f(pv.u[j]) * wz;
  }
  U8 ov;
  float li = linv[h];
#pragma unroll
  for (int j = 0; j < 8; j++) ov.u[j] = f2bf(acc[j] * li);
  *(short8v*)&fine[(size_t)q * fstr + c0] = ov.v;
}

// ---------------- GEMM v4: 128x128 tile, BK=64, double-buffered LDS with ----------------
// counted vmcnt (T3/T4-lite) + bijective XCD-chunked block remap (T1, m204).
// Round-2 post-mortem: 2-barrier structure drains vmcnt(0) every K-step
// (600-900cy L2-miss latency, MfmaUtil 16%). Now: 2 stages in flight; per step
// wait vmcnt(8) = only the OLDER tile's 8 loads; raw s_barrier (no implicit
// drain); lgkmcnt(0)+barrier guards the WAR before re-staging (rule #18:
// sched_barrier(0) after each wait to pin ordering).
// mode 0: bf16 = v+bias ; 1: bf16 = gelu(v+bias) ; 2: f32 = res + gvec*(v+bias)
// mode 3: bf16 raw partial at out + z*M*ldc (split-K)

__global__ __launch_bounds__(256, 2) void gemm3(const unsigned short* __restrict__ A, int lda,
    const unsigned short* __restrict__ Wt, const float* __restrict__ bias,
    void* __restrict__ outv, int ldc, const float* __restrict__ res,
    const float* __restrict__ gvec, int M, int N, int K, int kchunk, int mode) {
  __shared__ unsigned short As[2][128 * 64];
  __shared__ unsigned short Bs[2][128 * 64];
  int tid = threadIdx.x;

  // XCD-chunked bijective remap (all gemm grids here have nwg % 8 == 0; with
  // blockIdx.z, z*nwg = 0 mod 8 so xcd = orig%8 still matches hw round-robin).
  int gx = gridDim.x, nwg = gx * gridDim.y;
  int orig = blockIdx.y * gx + blockIdx.x;
  int q8 = nwg >> 3, r8 = nwg & 7;
  int xcd = orig & 7, sub = orig >> 3;
  int logical = (xcd < r8 ? xcd * (q8 + 1) : r8 * (q8 + 1) + (xcd - r8) * q8) + sub;
  int m0 = (logical % gx) * 128, n0 = (logical / gx) * 128;

  int wave = tid >> 6, lane = tid & 63;
  int quad = lane >> 4, l16 = lane & 15;
  int wm = (wave & 1) * 64, wn = (wave >> 1) * 64;
  int k0 = blockIdx.z * kchunk;
  int k1 = k0 + kchunk; if (k1 > K) k1 = K;

  int rofs = lane >> 3;                      // row within 8-row group
  int schunk = (lane & 7) ^ rofs;            // xor-swizzled 16B chunk read by this lane
  const unsigned short* Ag = A + (long)(m0 + wave * 32 + rofs) * lda + schunk * 8;
  const unsigned short* Bg = Wt + (long)(n0 + wave * 32 + rofs) * (long)K + schunk * 8;

  f32x4 acc[4][4];
#pragma unroll
  for (int mt = 0; mt < 4; mt++)
#pragma unroll
    for (int nt = 0; nt < 4; nt++) acc[mt][nt] = (f32x4){0.f, 0.f, 0.f, 0.f};

  int nk = (k1 - k0) >> 6;  // all K/kchunk here are multiples of 64
  auto stage = [&](int buf, int kb) {
#pragma unroll
    for (int j = 0; j < 4; j++) {
      gld16(Ag + (long)(j * 8) * lda + kb, &As[buf][(wave * 32 + j * 8) * 64]);
      gld16(Bg + (long)(j * 8) * K + kb, &Bs[buf][(wave * 32 + j * 8) * 64]);
    }
  };
  stage(0, k0);
  if (nk > 1) stage(1, k0 + 64);

  for (int t = 0; t < nk; ++t) {
    // wait only the OLDER tile's 8 loads (8 newer stay in flight across barrier)
    if (t < nk - 1) asm volatile("s_waitcnt vmcnt(8)" ::: "memory");
    else            asm volatile("s_waitcnt vmcnt(0)" ::: "memory");
    __builtin_amdgcn_s_barrier();
    __builtin_amdgcn_sched_barrier(0);
    const unsigned short* Asb = As[t & 1];
    const unsigned short* Bsb = Bs[t & 1];
#pragma unroll
    for (int ks = 0; ks < 2; ks++) {
      short8v af[4], bfr[4];
#pragma unroll
      for (int mt = 0; mt < 4; mt++) {
        int rr = wm + mt * 16 + l16;
        af[mt] = *(const short8v*)&Asb[rr * 64 + (((ks * 4 + quad) ^ (rr & 7)) * 8)];
      }
#pragma unroll
      for (int nt = 0; nt < 4; nt++) {
        int rr = wn + nt * 16 + l16;
        bfr[nt] = *(const short8v*)&Bsb[rr * 64 + (((ks * 4 + quad) ^ (rr & 7)) * 8)];
      }
#pragma unroll
      for (int mt = 0; mt < 4; mt++)
#pragma unroll
        for (int nt = 0; nt < 4; nt++)
          acc[mt][nt] = __builtin_amdgcn_mfma_f32_16x16x32_bf16(af[mt], bfr[nt], acc[mt][nt], 0, 0, 0);
    }
    if (t + 2 < nk) {
      // all waves' ds_reads of buf[t&1] must COMPLETE before overwrite
      asm volatile("s_waitcnt lgkmcnt(0)" ::: "memory");
      __builtin_amdgcn_s_barrier();
      __builtin_amdgcn_sched_barrier(0);
      stage(t & 1, k0 + (t + 2) * 64);
    }
  }

  long zoff = (mode == 3) ? (long)blockIdx.z * M * (long)ldc : 0;
#pragma unroll
  for (int mt = 0; mt < 4; mt++)
#pragma unroll
    for (int nt = 0; nt < 4; nt++)
#pragma unroll
      for (int r = 0; r < 4; r++) {
        int row = m0 + wm + mt * 16 + quad * 4 + r;
        int col = n0 + wn + nt * 16 + l16;
        float v = acc[mt][nt][r];
        if (bias) v += bias[col];
        if (mode == 1) {
          float z = 0.7978845608028654f * (v + 0.044715f * v * v * v);
          float e2 = __expf(2.f * z);
          float th_ = 1.f - 2.f / (e2 + 1.f);
          v = 0.5f * v * (1.f + th_);
        }
        long idx = (long)row * ldc + col;
        if (mode == 2) {
          float gv = gvec ? gvec[col] : 1.f;
          ((float*)outv)[idx] = res[idx] + gv * v;
        } else {
          ((unsigned short*)outv)[zoff + idx] = f2bf(v);
        }
      }
}

// split-K reduce: out = hid + gvec[col]*(sum_z parts + b2[col])
__global__ void reduce_splitk(const unsigned short* __restrict__ p, int nsplit,
                              const float* __restrict__ hid, const float* __restrict__ b2,
                              const float* __restrict__ gvec, float* __restrict__ out) {
  int i = blockIdx.x * 256 + threadIdx.x;  // SQ*DIMH
  int c = i % DIMH;
  float s = 0.f;
  for (int z = 0; z < nsplit; z++) s += bf2f(p[(long)z * SQ * DIMH + i]);
  out[i] = hid[i] + gvec[c] * (s + b2[c]);
}

// ---------------- launcher ----------------

extern "C" void kernel_launch(void* const* d_in, const int* in_sizes, int n_in,
                              void* d_out, int out_size, void* d_ws, size_t ws_size,
                              hipStream_t stream) {
  (void)in_sizes; (void)n_in; (void)out_size;
  const float* hs   = (const float*)d_in[0];
  const float* enc  = (const float*)d_in[1];
  const float* temb = (const float*)d_in[2];
  const float* rc   = (const float*)d_in[3];
  const float* rsn  = (const float*)d_in[4];
  const float* sst  = (const float*)d_in[5];
  const float* Wq = (const float*)d_in[6];   const float* bq = (const float*)d_in[7];
  const float* Wk = (const float*)d_in[8];   const float* bk = (const float*)d_in[9];
  const float* Wv = (const float*)d_in[10];  const float* bv = (const float*)d_in[11];
  const float* Wg = (const float*)d_in[12];  const float* bg = (const float*)d_in[13];
  const float* Wo = (const float*)d_in[14];  const float* bo = (const float*)d_in[15];
  const float* nq_w = (const float*)d_in[16];  const float* nk_w = (const float*)d_in[17];
  const float* saln_w = (const float*)d_in[18]; const float* saln_b = (const float*)d_in[19];
  const float* cWq = (const float*)d_in[20]; const float* cbq = (const float*)d_in[21];
  const float* cWk = (const float*)d_in[22]; const float* cbk = (const float*)d_in[23];
  const float* cWv = (const float*)d_in[24]; const float* cbv = (const float*)d_in[25];
  const float* cWo = (const float*)d_in[26]; const float* cbo = (const float*)d_in[27];
  const float* cnq_w = (const float*)d_in[28]; const float* cnk_w = (const float*)d_in[29];
  const float* W1 = (const float*)d_in[30];  const float* b1 = (const float*)d_in[31];
  const float* W2 = (const float*)d_in[32];  const float* b2 = (const float*)d_in[33];
  float* outp = (float*)d_out;
  const float attn_scale = 0.08838834764831845f;  // 1/sqrt(128)

  char* base = (char*)d_ws;
  size_t off = 0;
  auto alloc = [&](size_t bytes) -> void* {
    void* p = (void*)(base + off);
    off += (bytes + 255) & ~(size_t)255;
    return p;
  };
  const long ACTE = (long)SQ * DIMH;                 // elements
  float* e     = (float*)alloc(6 * DIMH * 4);
  float* bias4 = (float*)alloc(4 * DIMH * 4);
  unsigned short* nbuf = (unsigned short*)alloc(ACTE * 2);
  unsigned short* R    = (unsigned short*)alloc((size_t)SQ * FFNH * 2);
  float* hid           = (float*)alloc(ACTE * 4);
  unsigned short* WT   = (unsigned short*)alloc((size_t)FFNH * DIMH * 2);
  unsigned short* vt   = (unsigned short*)alloc((size_t)NH * DH * SQ * 2);
  unsigned short* encb = (unsigned short*)alloc((size_t)SKV * DIMH * 2);
  float* qc  = (float*)alloc(32 * DIMH * 4);
  float* kc  = (float*)alloc(32 * DIMH * 4);
  float* vc  = (float*)alloc(32 * DIMH * 4);
  float* cob = (float*)alloc(32 * DIMH * 4);
  float* mlbuf = (float*)alloc((size_t)4 * NH * SQ * 2 * 4);  // flash-split (m,l)
  size_t fixed_off = off;
  int nsplit = 4;
  unsigned short* parts = (unsigned short*)alloc((size_t)4 * ACTE * 2);
  if (off > ws_size) { off = fixed_off; nsplit = 2; parts = (unsigned short*)alloc((size_t)2 * ACTE * 2); }
  if (off > ws_size) { nsplit = 1; }
  // attention KV-split factor: 2 -> 768 blocks = 3 blocks/CU (the LDS limit)
  int asplit = (nsplit >= 2) ? 2 : 1;

  unsigned short* qkvg = R;
  unsigned short* qb   = R;                       // col 0    (stride 6144)
  unsigned short* kb   = R + DIMH;                // col 1536
  unsigned short* vb   = R + 2 * DIMH;            // col 3072
  unsigned short* gb   = R + 3 * DIMH;            // col 4608
  unsigned short* fine = R + 4 * ACTE;            // contiguous stride 1536
  unsigned short* qb2  = R;                       // cross-attn, stride 1536
  unsigned short* kb2  = R + ACTE;
  unsigned short* vb2  = R + ACTE + (long)SKV * DIMH;
  unsigned short* f1   = R;

  prep_e<<<36, 256, 0, stream>>>(sst, temb, e);
  concat4<<<24, 256, 0, stream>>>(bq, bk, bv, bg, bias4);

  layernorm_affine<<<SQ, 256, 0, stream>>>(hs, nbuf, e + DIMH, e, 1.f);

  dim3 tsq(DIMH / 32, DIMH / 32);
  transpose_bf16<<<tsq, 256, 0, stream>>>(Wq, WT + 0L * DIMH * DIMH, DIMH, DIMH);
  transpose_bf16<<<tsq, 256, 0, stream>>>(Wk, WT + 1L * DIMH * DIMH, DIMH, DIMH);
  transpose_bf16<<<tsq, 256, 0, stream>>>(Wv, WT + 2L * DIMH * DIMH, DIMH, DIMH);
  transpose_bf16<<<tsq, 256, 0, stream>>>(Wg, WT + 3L * DIMH * DIMH, DIMH, DIMH);
  gemm3<<<dim3(SQ / 128, 4 * DIMH / 128), 256, 0, stream>>>(
      nbuf, DIMH, WT, bias4, qkvg, 4 * DIMH, nullptr, nullptr, SQ, 4 * DIMH, DIMH, DIMH, 0);

  // q pre-scaled by 1/sqrt(D); k unscaled
  rms_rope<<<SQ, 256, 0, stream>>>(qb, 4 * DIMH, nq_w, rc, rsn, 1, attn_scale);
  rms_rope<<<SQ, 256, 0, stream>>>(kb, 4 * DIMH, nk_w, rc, rsn, 1, 1.f);

  pool64<<<dim3(6, 32), 256, 0, stream>>>(qb, 4 * DIMH, qc);
  pool64<<<dim3(6, 32), 256, 0, stream>>>(kb, 4 * DIMH, kc);
  pool64<<<dim3(6, 32), 256, 0, stream>>>(vb, 4 * DIMH, vc);

  vtrans<<<dim3(SQ / 32, DIMH / 32), 256, 0, stream>>>(vb, 4 * DIMH, vt, SQ);
  if (asplit > 1) {
    flash3<<<dim3(SQ / 64, NH, asplit), 256, 0, stream>>>(qb, 4 * DIMH, kb, 4 * DIMH, vt,
        parts, DIMH, SQ, mlbuf, ACTE, SQ / asplit);
    coarse_attn<<<NH, 256, 0, stream>>>(qc, kc, vc, cob);
    attn_combine<<<SQ, 192, 0, stream>>>(parts, mlbuf, asplit, fine, DIMH);
  } else {
    flash3<<<dim3(SQ / 64, NH), 256, 0, stream>>>(qb, 4 * DIMH, kb, 4 * DIMH, vt,
                                                  fine, DIMH, SQ, nullptr, 0, SQ);
    coarse_attn<<<NH, 256, 0, stream>>>(qc, kc, vc, cob);
  }
  combine_fine<<<SQ * DIMH / 256, 256, 0, stream>>>(fine, cob, gb, 4 * DIMH);

  transpose_bf16<<<tsq, 256, 0, stream>>>(Wo, WT, DIMH, DIMH);
  gemm3<<<dim3(SQ / 128, DIMH / 128), 256, 0, stream>>>(
      fine, DIMH, WT, bo, hid, DIMH, hs, e + 2 * DIMH, SQ, DIMH, DIMH, DIMH, 2);

  layernorm_affine<<<SQ, 256, 0, stream>>>(hid, nbuf, saln_w, saln_b, 0.f);
  transpose_bf16<<<tsq, 256, 0, stream>>>(cWq, WT, DIMH, DIMH);
  gemm3<<<dim3(SQ / 128, DIMH / 128), 256, 0, stream>>>(
      nbuf, DIMH, WT, cbq, qb2, DIMH, nullptr, nullptr, SQ, DIMH, DIMH, DIMH, 0);
  rms_rope<<<SQ, 256, 0, stream>>>(qb2, DIMH, cnq_w, nullptr, nullptr, 0, attn_scale);

  cast_f32_bf16<<<SKV * DIMH / 256, 256, 0, stream>>>(enc, encb, SKV * DIMH);
  transpose_bf16<<<tsq, 256, 0, stream>>>(cWk, WT, DIMH, DIMH);
  gemm3<<<dim3(SKV / 128, DIMH / 128), 256, 0, stream>>>(
      encb, DIMH, WT, cbk, kb2, DIMH, nullptr, nullptr, SKV, DIMH, DIMH, DIMH, 0);
  transpose_bf16<<<tsq, 256, 0, stream>>>(cWv, WT, DIMH, DIMH);
  gemm3<<<dim3(SKV / 128, DIMH / 128), 256, 0, stream>>>(
      encb, DIMH, WT, cbv, vb2, DIMH, nullptr, nullptr, SKV, DIMH, DIMH, DIMH, 0);
  rms_rope<<<SKV, 256, 0, stream>>>(kb2, DIMH, cnk_w, nullptr, nullptr, 0, 1.f);

  vtrans<<<dim3(SKV / 32, DIMH / 32), 256, 0, stream>>>(vb2, DIMH, vt, SKV);
  if (asplit > 1) {
    flash3<<<dim3(SQ / 64, NH, asplit), 256, 0, stream>>>(qb2, DIMH, kb2, DIMH, vt,
        parts, DIMH, SKV, mlbuf, ACTE, SKV / asplit);
    attn_combine<<<SQ, 192, 0, stream>>>(parts, mlbuf, asplit, fine, DIMH);
  } else {
    flash3<<<dim3(SQ / 64, NH), 256, 0, stream>>>(qb2, DIMH, kb2, DIMH, vt,
                                                  fine, DIMH, SKV, nullptr, 0, SKV);
  }
  transpose_bf16<<<tsq, 256, 0, stream>>>(cWo, WT, DIMH, DIMH);
  gemm3<<<dim3(SQ / 128, DIMH / 128), 256, 0, stream>>>(
      fine, DIMH, WT, cbo, hid, DIMH, hid, nullptr, SQ, DIMH, DIMH, DIMH, 2);

  layernorm_affine<<<SQ, 256, 0, stream>>>(hid, nbuf, e + 4 * DIMH, e + 3 * DIMH, 1.f);
  transpose_bf16<<<dim3(FFNH / 32, DIMH / 32), 256, 0, stream>>>(W1, WT, DIMH, FFNH);
  gemm3<<<dim3(SQ / 128, FFNH / 128), 256, 0, stream>>>(
      nbuf, DIMH, WT, b1, f1, FFNH, nullptr, nullptr, SQ, FFNH, DIMH, DIMH, 1);
  transpose_bf16<<<dim3(DIMH / 32, FFNH / 32), 256, 0, stream>>>(W2, WT, FFNH, DIMH);
  if (nsplit == 1) {
    gemm3<<<dim3(SQ / 128, DIMH / 128), 256, 0, stream>>>(
        f1, FFNH, WT, b2, outp, DIMH, hid, e + 5 * DIMH, SQ, DIMH, FFNH, FFNH, 2);
  } else {
    gemm3<<<dim3(SQ / 128, DIMH / 128, nsplit), 256, 0, stream>>>(
        f1, FFNH, WT, nullptr, parts, DIMH, nullptr, nullptr, SQ, DIMH, FFNH, FFNH / nsplit, 3);
    reduce_splitk<<<SQ * DIMH / 256, 256, 0, stream>>>(parts, nsplit, hid, b2,
                                                       e + 5 * DIMH, outp);
  }
}